// Round 11
// baseline (462.876 us; speedup 1.0000x reference)
//
#include <hip/hip_runtime.h>
#include <math.h>

// ---------------------------------------------------------------------------
// GAT 4-layer forward.
// GEMMs: bf16 MFMA 2-term split (C ~ Ah*Wh + Al*Wh) -> fp32 acc; 64x128 tile;
// alpha dots fused in epilogue. h stored fp16.
// Edge weights precomputed edge-parallel (k_wcomp: coalesced col/rid reads,
// L2-hot alpha tables). Aggregation (phase B): CSR per-dst wave, loads
// precomputed weights coalesced, readlane/LDS broadcast, 1 edge/iter gather.
// ---------------------------------------------------------------------------

typedef __attribute__((ext_vector_type(8))) short short8;
typedef __attribute__((ext_vector_type(4))) float f32x4;

__device__ __forceinline__ unsigned short f2bf(float f) {
  unsigned int u = __builtin_bit_cast(unsigned int, f);
  unsigned int r = u + 0x7FFFu + ((u >> 16) & 1u);   // RNE
  return (unsigned short)(r >> 16);
}
__device__ __forceinline__ float bf2f(unsigned short h) {
  unsigned int u = ((unsigned int)h) << 16;
  return __builtin_bit_cast(float, u);
}
__device__ __forceinline__ unsigned short f2h(float f) {
  _Float16 h = (_Float16)f;
  return __builtin_bit_cast(unsigned short, h);
}
__device__ __forceinline__ float h2f(unsigned short u) {
  return (float)__builtin_bit_cast(_Float16, u);
}

__device__ __forceinline__ void gload16(const unsigned short* g, unsigned short* l) {
  __builtin_amdgcn_global_load_lds(
      (const __attribute__((address_space(1))) void*)g,
      (__attribute__((address_space(3))) void*)l, 16, 0, 0);
}

// ---------------- MFMA GEMM: C[M,Nc] = A2[M,2K] @ W2t[Ncpad,2K]^T ----------
// 64x128 tile, 4 waves (2 row-halves x 2 col-halves), LDS 24 KB.
template<int H>
__global__ __launch_bounds__(256) void k_gemm_mfma(
    const unsigned short* __restrict__ A2, const unsigned short* __restrict__ Wt,
    unsigned short* __restrict__ C, const float* __restrict__ avec_s,
    const float* __restrict__ avec_d, float* __restrict__ outS,
    float* __restrict__ outD, int M, int Kb, int Nc)
{
  __shared__ unsigned short lds[12288];     // 24 KB: As[64][64] | Bs[128][64]
  unsigned short* As = lds;
  unsigned short* Bs = lds + 4096;
  const int tid = threadIdx.x;
  const int w = tid >> 6, l = tid & 63;
  const int row0 = blockIdx.x * 64, col0 = blockIdx.y * 128;
  const int wr = w >> 1, wc = w & 1;
  const int fr = l & 15, kg = l >> 4;
  const int xr = (fr & 7) << 4;                   // read-side XOR (bytes)
  const int sK = 2 * Kb;
  const int csrc = 8 * ((l & 7) ^ ((l >> 3) & 7));    // pre-swizzled src col
  const int lrow = l >> 3;                        // 8 lanes per row

  f32x4 acc[2][4];
  #pragma unroll
  for (int i = 0; i < 2; i++)
    #pragma unroll
    for (int j = 0; j < 4; j++) acc[i][j] = (f32x4){0.f, 0.f, 0.f, 0.f};

  for (int kp = 0; kp < sK; kp += 64) {
    #pragma unroll
    for (int i = 0; i < 2; i++) {               // A: 8 KB
      int q = w * 2 + i;
      gload16(&A2[(size_t)(row0 + q * 8 + lrow) * sK + (kp + csrc)], &As[q * 512]);
    }
    #pragma unroll
    for (int i = 0; i < 4; i++) {               // B: 16 KB
      int q = w * 4 + i;
      gload16(&Wt[(size_t)(col0 + q * 8 + lrow) * sK + (kp + csrc)], &Bs[q * 512]);
    }
    __syncthreads();
    #pragma unroll
    for (int kk = 0; kk < 2; kk++) {
      short8 a[2], b[4];
      #pragma unroll
      for (int mi = 0; mi < 2; mi++) {
        int r = wr * 32 + mi * 16 + fr;
        int off = r * 128 + ((kk * 64 + kg * 16) ^ xr);
        a[mi] = *(const short8*)((const char*)As + off);
      }
      #pragma unroll
      for (int ni = 0; ni < 4; ni++) {
        int c = wc * 64 + ni * 16 + fr;
        int off = c * 128 + ((kk * 64 + kg * 16) ^ xr);
        b[ni] = *(const short8*)((const char*)Bs + off);
      }
      #pragma unroll
      for (int mi = 0; mi < 2; mi++)
        #pragma unroll
        for (int ni = 0; ni < 4; ni++)
          acc[mi][ni] = __builtin_amdgcn_mfma_f32_16x16x32_bf16(
              a[mi], b[ni], acc[mi][ni], 0, 0, 0);
    }
    __syncthreads();
  }

  // ---- epilogue: acc -> swizzled LDS C-tile 64x128 fp16 ----
  #pragma unroll
  for (int mi = 0; mi < 2; mi++)
    #pragma unroll
    for (int ni = 0; ni < 4; ni++)
      #pragma unroll
      for (int rr = 0; rr < 4; rr++) {
        int row = wr * 32 + mi * 16 + kg * 4 + rr;
        int c = wc * 64 + ni * 16 + fr;
        int sc = c ^ (((row >> 1) & 7) << 3);
        lds[row * 128 + sc] = f2h(acc[mi][ni][rr]);
      }
  __syncthreads();

  // ---- coalesced store + fused alpha ----
  constexpr int RW = (H == 8) ? 4 : 16;
  const int Ch = Nc / H;
  const int rbase = tid >> 4;                     // 0..15
  const int cc = tid & 15;
  const int c0 = cc * 8;
  const int gc0 = col0 + c0;
  float as8[8], ad8[8];
  #pragma unroll
  for (int j = 0; j < 8; j++) {
    bool ok = (gc0 + j) < Nc;
    as8[j] = ok ? avec_s[gc0 + j] : 0.f;
    ad8[j] = ok ? avec_d[gc0 + j] : 0.f;
  }
  #pragma unroll
  for (int i = 0; i < 4; i++) {
    int row = rbase + i * 16;
    int gr = row0 + row;
    int scc = c0 ^ (((row >> 1) & 7) << 3);
    short8 cv = *(const short8*)&lds[row * 128 + scc];
    if (gr < M && gc0 < Nc)
      *(short8*)&C[(size_t)gr * Nc + gc0] = cv;
    float ps = 0.f, pd = 0.f;
    #pragma unroll
    for (int j = 0; j < 8; j++) {
      float cf = h2f((unsigned short)cv[j]);
      ps = fmaf(cf, as8[j], ps);
      pd = fmaf(cf, ad8[j], pd);
    }
    #pragma unroll
    for (int off = 1; off < RW; off <<= 1) {
      ps += __shfl_xor(ps, off);
      pd += __shfl_xor(pd, off);
    }
    if ((tid & (RW - 1)) == 0 && gr < M) {
      int head = gc0 / Ch;                        // 0-add on OOB pad cols
      atomicAdd(&outS[gr * H + head], ps);
      atomicAdd(&outD[gr * H + head], pd);
    }
  }
}

// ---------------- pack layer-1 input: x fp32 [N,128] -> A2 [Mpad,256] ------
__global__ __launch_bounds__(256) void k_packX(const float* __restrict__ x,
    unsigned short* __restrict__ A2, int N, int Mpad)
{
  int row = blockIdx.x * 8 + (threadIdx.x >> 5);
  int c = (threadIdx.x & 31) * 4;
  if (row >= Mpad) return;
  float4 v = make_float4(0.f, 0.f, 0.f, 0.f);
  if (row < N) v = *(const float4*)&x[(size_t)row * 128 + c];
  float f[4] = {v.x, v.y, v.z, v.w};
  unsigned short hi[4], lo[4];
  #pragma unroll
  for (int i = 0; i < 4; i++) {
    hi[i] = f2bf(f[i]);
    lo[i] = f2bf(f[i] - bf2f(hi[i]));
  }
  size_t base = (size_t)row * 256 + c;
  *(uint2*)&A2[base] = make_uint2((unsigned)hi[0] | ((unsigned)hi[1] << 16),
                                  (unsigned)hi[2] | ((unsigned)hi[3] << 16));
  *(uint2*)&A2[base + 128] = make_uint2((unsigned)lo[0] | ((unsigned)lo[1] << 16),
                                        (unsigned)lo[2] | ((unsigned)lo[3] << 16));
}

// ---------------- pack W fp32 [K,NC] -> W2t bf16 [NCPAD,2K] = [Wh|Wh] ------
__global__ void k_packW(const float* __restrict__ W, unsigned short* __restrict__ Wt,
                        int K, int NC, int NCPAD)
{
  int idx = blockIdx.x * 256 + threadIdx.x;
  int K2 = 2 * K;
  if (idx >= NCPAD * K2) return;
  int c = idx / K2, kp = idx % K2;
  unsigned short o = 0;
  if (c < NC) o = f2bf(W[(size_t)(kp % K) * NC + c]);
  Wt[(size_t)c * K2 + kp] = o;
}

// ---- edge-parallel weight precompute: wbuf[e*H+h] = exp(leaky(aS+aD)) -----
template<int H>
__global__ void k_wcomp(const float* __restrict__ aS, const float* __restrict__ aD,
    const int* __restrict__ col, const int* __restrict__ rid,
    float* __restrict__ wbuf, int M)
{
  int idx = blockIdx.x * 256 + threadIdx.x;
  if (idx >= M) return;
  int e = idx / H, hd = idx % H;                  // H=1: folds away
  int s = col[e], r = rid[e];
  float lg = aS[s * H + hd] + aD[r * H + hd];
  lg = fmaxf(lg, 0.2f * lg);                      // leaky_relu
  wbuf[idx] = __expf(lg);                         // no max shift: |lg| bounded
}

// ---- segment softmax + weighted aggregate, one wave per dst row -----------
// Phase B: weights precomputed in wbuf (coalesced load); den via shuffles;
// gather 1 edge/iter with readlane (H=1) / LDS-table (H=8) broadcast.
template<int H, int HC, int ELU, int SPLIT>
__global__ __launch_bounds__(256) void k_aggregate(const unsigned short* __restrict__ h,
    const float* __restrict__ wbuf,
    const int* __restrict__ rowptr, const int* __restrict__ col,
    const float* __restrict__ bias, float* __restrict__ xout,
    unsigned short* __restrict__ a2out, int N)
{
  constexpr int VEC = HC / 64;            // 4 (HC=256) or 1 (HC=64)
  constexpr int C = HC / H;
  constexpr int CH = (H == 8) ? 8 : 64;   // edges per chunk
  __shared__ float wlds[4][64];           // H=8: per-wave [eo*8+hd] weights
  int wave = threadIdx.x >> 6, lane = threadIdx.x & 63;
  int row = blockIdx.x * 4 + wave;
  if (row >= N) return;
  const int cb = lane * VEC;
  const int hdg = cb / C;                 // gather-phase head of this lane
  int s0 = rowptr[row], s1 = rowptr[row + 1];

  float den = 0.f;
  float acc[VEC];
  #pragma unroll
  for (int v = 0; v < VEC; v++) acc[v] = 0.f;

  for (int base = s0; base < s1; base += CH) {
    int cnt = min(CH, s1 - base);
    // ---- load chunk weights (coalesced) + cols ----
    int eo = (H == 8) ? (lane >> 3) : lane;
    bool valid = eo < cnt;
    int s = col[valid ? (base + eo) : (s1 - 1)];
    float wv = valid ? wbuf[(size_t)base * H + lane] : 0.f;  // (base+eo)*H+hd
    float d = wv;
    if constexpr (H == 8) {
      d += __shfl_xor(d, 8); d += __shfl_xor(d, 16); d += __shfl_xor(d, 32);
      wlds[wave][lane] = wv;              // [eo*8+hd]
    } else {
      #pragma unroll
      for (int off = 1; off < 64; off <<= 1) d += __shfl_xor(d, off);
    }
    den += d;                             // H==8: lane holds den[lane&7]
    if (H == 8) {
      asm volatile("s_waitcnt lgkmcnt(0)" ::: "memory");  // wave-local order
    }
    // ---- gather ----
    #pragma unroll 2
    for (int j = 0; j < cnt; j++) {
      int sj = __builtin_amdgcn_readlane(s, (H == 8) ? (j * 8) : j);
      float wj;
      if constexpr (H == 8) {
        wj = wlds[wave][j * 8 + hdg];     // 8 banks, 8-lane broadcast each
      } else {
        wj = __builtin_bit_cast(float,
              __builtin_amdgcn_readlane(__builtin_bit_cast(int, wv), j));
      }
      if constexpr (VEC == 4) {
        uint2 raw = *(const uint2*)&h[(size_t)sj * HC + cb];
        acc[0] = fmaf(wj, h2f((unsigned short)(raw.x & 0xFFFF)), acc[0]);
        acc[1] = fmaf(wj, h2f((unsigned short)(raw.x >> 16)),    acc[1]);
        acc[2] = fmaf(wj, h2f((unsigned short)(raw.y & 0xFFFF)), acc[2]);
        acc[3] = fmaf(wj, h2f((unsigned short)(raw.y >> 16)),    acc[3]);
      } else {
        acc[0] = fmaf(wj, h2f(h[(size_t)sj * HC + cb]), acc[0]);
      }
    }
  }
  if (H == 8) den = __shfl(den, hdg);     // den[h] lives at lane h
  float inv = 1.f / (den + 1e-16f);
  float o[VEC];
  #pragma unroll
  for (int v = 0; v < VEC; v++) {
    float t = acc[v] * inv + bias[cb + v];
    if (ELU) t = t > 0.f ? t : expm1f(t);
    o[v] = t;
  }
  if constexpr (SPLIT) {
    unsigned short hi[4], lo[4];
    #pragma unroll
    for (int v = 0; v < 4; v++) {
      hi[v] = f2bf(o[v]);
      lo[v] = f2bf(o[v] - bf2f(hi[v]));
    }
    size_t b2 = (size_t)row * (2 * HC) + cb;
    *(uint2*)&a2out[b2] = make_uint2((unsigned)hi[0] | ((unsigned)hi[1] << 16),
                                     (unsigned)hi[2] | ((unsigned)hi[3] << 16));
    *(uint2*)&a2out[b2 + HC] = make_uint2((unsigned)lo[0] | ((unsigned)lo[1] << 16),
                                          (unsigned)lo[2] | ((unsigned)lo[3] << 16));
  } else if constexpr (VEC == 4) {
    *(float4*)&xout[(size_t)row * HC + cb] = make_float4(o[0], o[1], o[2], o[3]);
  } else {
    xout[(size_t)row * HC + cb] = o[0];
  }
}

// ------------------------- CSR construction --------------------------------
__global__ void k_init(int* deg, float* pool, unsigned short* A2, int N, int B,
                       int Mpad) {
  int i = blockIdx.x * 256 + threadIdx.x;
  if (i < N) deg[i] = 1;                  // self loop
  if (i < B * 64) pool[i] = 0.f;
  int padn = (Mpad - N) * 512;            // zero stride-512 pad rows of A2
  if (i < padn) A2[(size_t)N * 512 + i] = 0;
}

__global__ void k_deg(const int* __restrict__ ei, int* deg, int E) {
  int e = blockIdx.x * 256 + threadIdx.x;
  if (e < E) atomicAdd(&deg[ei[E + e]], 1);
}

// counts per graph via binary search over the SORTED batch array
__global__ void k_counts(const int* __restrict__ bat, int* cnt, int N, int B) {
  int b = threadIdx.x;
  if (b >= B) return;
  int lo0 = 0, hi0 = N;
  while (lo0 < hi0) { int mid = (lo0 + hi0) >> 1; if (bat[mid] < b) lo0 = mid + 1; else hi0 = mid; }
  int lo1 = lo0, hi1 = N;
  while (lo1 < hi1) { int mid = (lo1 + hi1) >> 1; if (bat[mid] < b + 1) lo1 = mid + 1; else hi1 = mid; }
  cnt[b] = lo1 - lo0;
}

__global__ __launch_bounds__(256) void k_scan1(const int* __restrict__ deg,
                                               int* csum, int N, int chunk) {
  int bid = blockIdx.x, t = threadIdx.x;
  int lo = bid * chunk, hi = min(lo + chunk, N);
  int s = 0;
  for (int i = lo + t; i < hi; i += 256) s += deg[i];
  #pragma unroll
  for (int off = 32; off; off >>= 1) s += __shfl_xor(s, off);
  __shared__ int sh[4];
  if ((t & 63) == 0) sh[t >> 6] = s;
  __syncthreads();
  if (t == 0) csum[bid] = sh[0] + sh[1] + sh[2] + sh[3];
}

__global__ __launch_bounds__(256) void k_scan2(const int* __restrict__ csum,
                                               int* coff) {
  __shared__ int s[256];
  int t = threadIdx.x;
  int v0 = csum[t];
  s[t] = v0;
  for (int off = 1; off < 256; off <<= 1) {
    __syncthreads();
    int v = (t >= off) ? s[t - off] : 0;
    __syncthreads();
    s[t] += v;
  }
  __syncthreads();
  coff[t] = s[t] - v0;
}

__global__ __launch_bounds__(256) void k_scan3(const int* __restrict__ deg,
    const int* __restrict__ coff, int* rowptr, int* cursor, int N, int chunk) {
  __shared__ int s[256];
  int bid = blockIdx.x, t = threadIdx.x;
  int i = bid * chunk + t;
  int v = (t < chunk && i < N) ? deg[i] : 0;
  s[t] = v;
  for (int off = 1; off < 256; off <<= 1) {
    __syncthreads();
    int x = (t >= off) ? s[t - off] : 0;
    __syncthreads();
    s[t] += x;
  }
  __syncthreads();
  int excl = s[t] - v + coff[bid];
  if (t < chunk && i < N) {
    rowptr[i] = excl;
    cursor[i] = excl;
    if (i == N - 1) rowptr[N] = excl + v;
  }
}

__global__ void k_scatter(const int* __restrict__ ei, int* cursor, int* col,
                          int* rid, int E, int N) {
  int idx = blockIdx.x * 256 + threadIdx.x;
  if (idx >= E + N) return;
  int s, d;
  if (idx < E) { s = ei[idx]; d = ei[E + idx]; }
  else         { s = d = idx - E; }
  int pos = atomicAdd(&cursor[d], 1);
  col[pos] = s;
  rid[pos] = d;
}

// ------------------------------ pooling ------------------------------------
__global__ __launch_bounds__(256) void k_pool(const float* __restrict__ xg,
    const int* __restrict__ bat, float* pool, int N) {
  int lane = threadIdx.x & 63, w = threadIdx.x >> 6;
  int base = (blockIdx.x * 4 + w) * 16;
  if (base >= N) return;
  int end = min(base + 16, N);
  float local = 0.f;
  int curb = bat[base];
  for (int n = base; n < end; n++) {
    int b = bat[n];
    if (b != curb) {
      atomicAdd(&pool[curb * 64 + lane], local);
      local = 0.f; curb = b;
    }
    local += xg[(size_t)n * 64 + lane];
  }
  atomicAdd(&pool[curb * 64 + lane], local);
}

__global__ void k_final(const float* __restrict__ pool, const int* __restrict__ cnt,
    const float* __restrict__ Wl, const float* __restrict__ bl,
    float* __restrict__ out, int B) {
  int lane = threadIdx.x;                 // 64 threads
  int c = (lane < B) ? cnt[lane] : 0;
  #pragma unroll
  for (int off = 32; off; off >>= 1) c = max(c, __shfl_xor(c, off));
  float invm = 1.f / (float)c;
  float wl = Wl[lane];
  for (int b = 0; b < B; b++) {
    float ps = pool[b * 64 + lane] * wl;
    #pragma unroll
    for (int off = 32; off; off >>= 1) ps += __shfl_xor(ps, off);
    if (lane == 0) out[b] = ps * invm + bl[0];
  }
}

// ---------------------------------------------------------------------------
extern "C" void kernel_launch(void* const* d_in, const int* in_sizes, int n_in,
                              void* d_out, int out_size, void* d_ws, size_t ws_size,
                              hipStream_t stream)
{
  (void)n_in; (void)ws_size;
  const float* x   = (const float*)d_in[0];
  const int*   ei  = (const int*)d_in[1];
  const int*   bat = (const int*)d_in[2];
  const float* W1  = (const float*)d_in[3];
  const float* as1 = (const float*)d_in[4];
  const float* ad1 = (const float*)d_in[5];
  const float* b1  = (const float*)d_in[6];
  const float* W2  = (const float*)d_in[7];
  const float* as2 = (const float*)d_in[8];
  const float* ad2 = (const float*)d_in[9];
  const float* b2  = (const float*)d_in[10];
  const float* W3  = (const float*)d_in[11];
  const float* as3 = (const float*)d_in[12];
  const float* ad3 = (const float*)d_in[13];
  const float* b3  = (const float*)d_in[14];
  const float* W4  = (const float*)d_in[15];
  const float* as4 = (const float*)d_in[16];
  const float* ad4 = (const float*)d_in[17];
  const float* b4  = (const float*)d_in[18];
  const float* Wl  = (const float*)d_in[19];
  const float* bl  = (const float*)d_in[20];
  float* out = (float*)d_out;

  const int N = in_sizes[0] / 128;
  const int E = in_sizes[1] / 2;
  const int B = out_size;
  const int Mpad = ((N + 127) / 128) * 128;
  const int EN = E + N;

  char* p = (char*)d_ws;
  auto alloc = [&](size_t bytes) -> void* {
    void* r = (void*)p;
    p += ((bytes + 255) & ~(size_t)255);
    return r;
  };
  unsigned short* A2 = (unsigned short*)alloc((size_t)Mpad * 512 * 2);
  unsigned short* hbuf = (unsigned short*)alloc((size_t)N * 256 * 2);
  unsigned short* w2t1 = (unsigned short*)alloc((size_t)256 * 512 * 2);
  unsigned short* w2t2 = (unsigned short*)alloc((size_t)256 * 512 * 2);
  unsigned short* w2t3 = (unsigned short*)alloc((size_t)256 * 512 * 2);
  unsigned short* w2t4 = (unsigned short*)alloc((size_t)128 * 512 * 2);
  float* aAll  = (float*)alloc((size_t)N * 22 * 4);
  float* aSb   = aAll;
  float* aDb   = aAll + (size_t)N * 11;
  float* wbuf  = (float*)alloc((size_t)EN * 8 * 4);
  int*   deg   = (int*)alloc((size_t)N * 4);
  int*   rowptr= (int*)alloc((size_t)(N + 1) * 4);
  int*   cursor= (int*)alloc((size_t)N * 4);
  int*   col   = (int*)alloc((size_t)EN * 4);
  int*   rid   = (int*)alloc((size_t)EN * 4);
  int*   csum  = (int*)alloc(256 * 4);
  int*   coff  = (int*)alloc(256 * 4);
  float* pool  = (float*)alloc((size_t)B * 64 * 4);
  int*   cnt   = (int*)alloc((size_t)B * 4);
  float* xpool = (float*)A2;              // layer-4 output reuses A2 (fp32 [N,64])

  const int chunk = (N + 255) / 256;
  dim3 T(256);

  // ---- CSR build + init ----
  k_init<<<dim3((N + 255) / 256), T, 0, stream>>>(deg, pool, A2, N, B, Mpad);
  k_deg<<<dim3((E + 255) / 256), T, 0, stream>>>(ei, deg, E);
  k_counts<<<dim3(1), dim3(64), 0, stream>>>(bat, cnt, N, B);
  k_scan1<<<dim3(256), T, 0, stream>>>(deg, csum, N, chunk);
  k_scan2<<<dim3(1), T, 0, stream>>>(csum, coff);
  k_scan3<<<dim3(256), T, 0, stream>>>(deg, coff, rowptr, cursor, N, chunk);
  k_scatter<<<dim3((EN + 255) / 256), T, 0, stream>>>(ei, cursor, col, rid, E, N);
  hipMemsetAsync(aAll, 0, (size_t)N * 22 * 4, stream);

  // ---- weight + input packing ----
  k_packX<<<dim3(Mpad / 8), T, 0, stream>>>(x, A2, N, Mpad);
  k_packW<<<dim3((256 * 256 + 255) / 256), T, 0, stream>>>(W1, w2t1, 128, 256, 256);
  k_packW<<<dim3((256 * 512 + 255) / 256), T, 0, stream>>>(W2, w2t2, 256, 256, 256);
  k_packW<<<dim3((256 * 512 + 255) / 256), T, 0, stream>>>(W3, w2t3, 256, 256, 256);
  k_packW<<<dim3((128 * 512 + 255) / 256), T, 0, stream>>>(W4, w2t4, 256, 64, 128);

  dim3 nwav((N + 3) / 4);
  dim3 g2(Mpad / 64, 2), g1(Mpad / 64, 1);
  dim3 gw8((EN * 8 + 255) / 256), gw1((EN + 255) / 256);

  // per-layer alpha buffers inside the arena
  float* aS1 = aSb;                 float* aD1 = aDb;                 // N*8
  float* aS2 = aSb + (size_t)N * 8; float* aD2 = aDb + (size_t)N * 8; // N
  float* aS3 = aSb + (size_t)N * 9; float* aD3 = aDb + (size_t)N * 9; // N
  float* aS4 = aSb + (size_t)N * 10;float* aD4 = aDb + (size_t)N * 10;// N

  // ---- layer 1: [N,128]@[128,256], H=8, ELU ----
  k_gemm_mfma<8><<<g2, T, 0, stream>>>(A2, w2t1, hbuf, as1, ad1, aS1, aD1, N, 128, 256);
  k_wcomp<8><<<gw8, T, 0, stream>>>(aS1, aD1, col, rid, wbuf, EN * 8);
  k_aggregate<8, 256, 1, 1><<<nwav, T, 0, stream>>>(hbuf, wbuf, rowptr, col, b1,
                                                    nullptr, A2, N);
  // ---- layer 2 ----
  k_gemm_mfma<1><<<g2, T, 0, stream>>>(A2, w2t2, hbuf, as2, ad2, aS2, aD2, N, 256, 256);
  k_wcomp<1><<<gw1, T, 0, stream>>>(aS2, aD2, col, rid, wbuf, EN);
  k_aggregate<1, 256, 1, 1><<<nwav, T, 0, stream>>>(hbuf, wbuf, rowptr, col, b2,
                                                    nullptr, A2, N);
  // ---- layer 3 ----
  k_gemm_mfma<1><<<g2, T, 0, stream>>>(A2, w2t3, hbuf, as3, ad3, aS3, aD3, N, 256, 256);
  k_wcomp<1><<<gw1, T, 0, stream>>>(aS3, aD3, col, rid, wbuf, EN);
  k_aggregate<1, 256, 1, 1><<<nwav, T, 0, stream>>>(hbuf, wbuf, rowptr, col, b3,
                                                    nullptr, A2, N);
  // ---- layer 4: [N,256]@[256,64], H=1, no ELU ----
  k_gemm_mfma<1><<<g1, T, 0, stream>>>(A2, w2t4, hbuf, as4, ad4, aS4, aD4, N, 256, 64);
  k_wcomp<1><<<gw1, T, 0, stream>>>(aS4, aD4, col, rid, wbuf, EN);
  k_aggregate<1, 64, 0, 0><<<nwav, T, 0, stream>>>(hbuf, wbuf, rowptr, col, b4,
                                                   xpool, nullptr, N);

  // ---- pooling + final linear ----
  k_pool<<<dim3((N + 63) / 64), T, 0, stream>>>(xpool, bat, pool, N);
  k_final<<<dim3(1), dim3(64), 0, stream>>>(pool, cnt, Wl, bl, out, B);
}

// Round 12
// 461.088 us; speedup vs baseline: 1.0039x; 1.0039x over previous
//
#include <hip/hip_runtime.h>
#include <math.h>

// ---------------------------------------------------------------------------
// GAT 4-layer forward.
// GEMMs: bf16 MFMA 2-term split (C ~ Ah*Wh + Al*Wh) -> fp32 acc; 64x128 tile;
// alpha dots fused in epilogue. h stored fp16.
// Edge weights precomputed edge-parallel (k_wcomp). Aggregation: CSR per-dst
// wave; readlane/LDS broadcast; gather inner loop uses v_fma_mix_f32 (packed
// fp16 ops) + 32-bit saddr offsets; unroll 4.
// ---------------------------------------------------------------------------

typedef __attribute__((ext_vector_type(8))) short short8;
typedef __attribute__((ext_vector_type(4))) float f32x4;

__device__ __forceinline__ unsigned short f2bf(float f) {
  unsigned int u = __builtin_bit_cast(unsigned int, f);
  unsigned int r = u + 0x7FFFu + ((u >> 16) & 1u);   // RNE
  return (unsigned short)(r >> 16);
}
__device__ __forceinline__ float bf2f(unsigned short h) {
  unsigned int u = ((unsigned int)h) << 16;
  return __builtin_bit_cast(float, u);
}
__device__ __forceinline__ unsigned short f2h(float f) {
  _Float16 h = (_Float16)f;
  return __builtin_bit_cast(unsigned short, h);
}
__device__ __forceinline__ float h2f(unsigned short u) {
  return (float)__builtin_bit_cast(_Float16, u);
}

// acc += (f16 lo/hi half of packed) * w   -- single VALU op each
__device__ __forceinline__ void fma_mix_lo(float& acc, unsigned int packed, float w) {
  asm("v_fma_mix_f32 %0, %1, %2, %0 op_sel_hi:[1,0,0]"
      : "+v"(acc) : "v"(packed), "v"(w));
}
__device__ __forceinline__ void fma_mix_hi(float& acc, unsigned int packed, float w) {
  asm("v_fma_mix_f32 %0, %1, %2, %0 op_sel:[1,0,0] op_sel_hi:[1,0,0]"
      : "+v"(acc) : "v"(packed), "v"(w));
}

__device__ __forceinline__ void gload16(const unsigned short* g, unsigned short* l) {
  __builtin_amdgcn_global_load_lds(
      (const __attribute__((address_space(1))) void*)g,
      (__attribute__((address_space(3))) void*)l, 16, 0, 0);
}

// ---------------- MFMA GEMM: C[M,Nc] = A2[M,2K] @ W2t[Ncpad,2K]^T ----------
// 64x128 tile, 4 waves (2 row-halves x 2 col-halves), LDS 24 KB.
template<int H>
__global__ __launch_bounds__(256) void k_gemm_mfma(
    const unsigned short* __restrict__ A2, const unsigned short* __restrict__ Wt,
    unsigned short* __restrict__ C, const float* __restrict__ avec_s,
    const float* __restrict__ avec_d, float* __restrict__ outS,
    float* __restrict__ outD, int M, int Kb, int Nc)
{
  __shared__ unsigned short lds[12288];     // 24 KB: As[64][64] | Bs[128][64]
  unsigned short* As = lds;
  unsigned short* Bs = lds + 4096;
  const int tid = threadIdx.x;
  const int w = tid >> 6, l = tid & 63;
  const int row0 = blockIdx.x * 64, col0 = blockIdx.y * 128;
  const int wr = w >> 1, wc = w & 1;
  const int fr = l & 15, kg = l >> 4;
  const int xr = (fr & 7) << 4;                   // read-side XOR (bytes)
  const int sK = 2 * Kb;
  const int csrc = 8 * ((l & 7) ^ ((l >> 3) & 7));    // pre-swizzled src col
  const int lrow = l >> 3;                        // 8 lanes per row

  f32x4 acc[2][4];
  #pragma unroll
  for (int i = 0; i < 2; i++)
    #pragma unroll
    for (int j = 0; j < 4; j++) acc[i][j] = (f32x4){0.f, 0.f, 0.f, 0.f};

  for (int kp = 0; kp < sK; kp += 64) {
    #pragma unroll
    for (int i = 0; i < 2; i++) {               // A: 8 KB
      int q = w * 2 + i;
      gload16(&A2[(size_t)(row0 + q * 8 + lrow) * sK + (kp + csrc)], &As[q * 512]);
    }
    #pragma unroll
    for (int i = 0; i < 4; i++) {               // B: 16 KB
      int q = w * 4 + i;
      gload16(&Wt[(size_t)(col0 + q * 8 + lrow) * sK + (kp + csrc)], &Bs[q * 512]);
    }
    __syncthreads();
    #pragma unroll
    for (int kk = 0; kk < 2; kk++) {
      short8 a[2], b[4];
      #pragma unroll
      for (int mi = 0; mi < 2; mi++) {
        int r = wr * 32 + mi * 16 + fr;
        int off = r * 128 + ((kk * 64 + kg * 16) ^ xr);
        a[mi] = *(const short8*)((const char*)As + off);
      }
      #pragma unroll
      for (int ni = 0; ni < 4; ni++) {
        int c = wc * 64 + ni * 16 + fr;
        int off = c * 128 + ((kk * 64 + kg * 16) ^ xr);
        b[ni] = *(const short8*)((const char*)Bs + off);
      }
      #pragma unroll
      for (int mi = 0; mi < 2; mi++)
        #pragma unroll
        for (int ni = 0; ni < 4; ni++)
          acc[mi][ni] = __builtin_amdgcn_mfma_f32_16x16x32_bf16(
              a[mi], b[ni], acc[mi][ni], 0, 0, 0);
    }
    __syncthreads();
  }

  // ---- epilogue: acc -> swizzled LDS C-tile 64x128 fp16 ----
  #pragma unroll
  for (int mi = 0; mi < 2; mi++)
    #pragma unroll
    for (int ni = 0; ni < 4; ni++)
      #pragma unroll
      for (int rr = 0; rr < 4; rr++) {
        int row = wr * 32 + mi * 16 + kg * 4 + rr;
        int c = wc * 64 + ni * 16 + fr;
        int sc = c ^ (((row >> 1) & 7) << 3);
        lds[row * 128 + sc] = f2h(acc[mi][ni][rr]);
      }
  __syncthreads();

  // ---- coalesced store + fused alpha ----
  constexpr int RW = (H == 8) ? 4 : 16;
  const int Ch = Nc / H;
  const int rbase = tid >> 4;                     // 0..15
  const int cc = tid & 15;
  const int c0 = cc * 8;
  const int gc0 = col0 + c0;
  float as8[8], ad8[8];
  #pragma unroll
  for (int j = 0; j < 8; j++) {
    bool ok = (gc0 + j) < Nc;
    as8[j] = ok ? avec_s[gc0 + j] : 0.f;
    ad8[j] = ok ? avec_d[gc0 + j] : 0.f;
  }
  #pragma unroll
  for (int i = 0; i < 4; i++) {
    int row = rbase + i * 16;
    int gr = row0 + row;
    int scc = c0 ^ (((row >> 1) & 7) << 3);
    short8 cv = *(const short8*)&lds[row * 128 + scc];
    if (gr < M && gc0 < Nc)
      *(short8*)&C[(size_t)gr * Nc + gc0] = cv;
    float ps = 0.f, pd = 0.f;
    #pragma unroll
    for (int j = 0; j < 8; j++) {
      float cf = h2f((unsigned short)cv[j]);
      ps = fmaf(cf, as8[j], ps);
      pd = fmaf(cf, ad8[j], pd);
    }
    #pragma unroll
    for (int off = 1; off < RW; off <<= 1) {
      ps += __shfl_xor(ps, off);
      pd += __shfl_xor(pd, off);
    }
    if ((tid & (RW - 1)) == 0 && gr < M) {
      int head = gc0 / Ch;                        // 0-add on OOB pad cols
      atomicAdd(&outS[gr * H + head], ps);
      atomicAdd(&outD[gr * H + head], pd);
    }
  }
}

// ---------------- pack layer-1 input: x fp32 [N,128] -> A2 [Mpad,256] ------
__global__ __launch_bounds__(256) void k_packX(const float* __restrict__ x,
    unsigned short* __restrict__ A2, int N, int Mpad)
{
  int row = blockIdx.x * 8 + (threadIdx.x >> 5);
  int c = (threadIdx.x & 31) * 4;
  if (row >= Mpad) return;
  float4 v = make_float4(0.f, 0.f, 0.f, 0.f);
  if (row < N) v = *(const float4*)&x[(size_t)row * 128 + c];
  float f[4] = {v.x, v.y, v.z, v.w};
  unsigned short hi[4], lo[4];
  #pragma unroll
  for (int i = 0; i < 4; i++) {
    hi[i] = f2bf(f[i]);
    lo[i] = f2bf(f[i] - bf2f(hi[i]));
  }
  size_t base = (size_t)row * 256 + c;
  *(uint2*)&A2[base] = make_uint2((unsigned)hi[0] | ((unsigned)hi[1] << 16),
                                  (unsigned)hi[2] | ((unsigned)hi[3] << 16));
  *(uint2*)&A2[base + 128] = make_uint2((unsigned)lo[0] | ((unsigned)lo[1] << 16),
                                        (unsigned)lo[2] | ((unsigned)lo[3] << 16));
}

// -------- pack all W fp32 -> bf16 [NCPAD,2K] = [Wh|Wh], one kernel ---------
__device__ __forceinline__ void packW_one(const float* __restrict__ W,
    unsigned short* __restrict__ Wt, int K, int NC, int idx)
{
  int K2 = 2 * K;
  int c = idx / K2, kp = idx % K2;
  unsigned short o = 0;
  if (c < NC) o = f2bf(W[(size_t)(kp % K) * NC + c]);
  Wt[(size_t)c * K2 + kp] = o;
}

__global__ void k_packW_all(const float* __restrict__ W1, const float* __restrict__ W2,
    const float* __restrict__ W3, const float* __restrict__ W4,
    unsigned short* __restrict__ t1, unsigned short* __restrict__ t2,
    unsigned short* __restrict__ t3, unsigned short* __restrict__ t4)
{
  int idx = blockIdx.x * 256 + threadIdx.x;
  if (idx < 65536)            packW_one(W1, t1, 128, 256, idx);
  else if (idx < 196608)      packW_one(W2, t2, 256, 256, idx - 65536);
  else if (idx < 327680)      packW_one(W3, t3, 256, 256, idx - 196608);
  else if (idx < 393216)      packW_one(W4, t4, 256,  64, idx - 327680);
}

// ---- edge-parallel weight precompute: wbuf[e*H+h] = exp(leaky(aS+aD)) -----
template<int H>
__global__ void k_wcomp(const float* __restrict__ aS, const float* __restrict__ aD,
    const int* __restrict__ col, const int* __restrict__ rid,
    float* __restrict__ wbuf, int M)
{
  int idx = blockIdx.x * 256 + threadIdx.x;
  if (idx >= M) return;
  int e = idx / H, hd = idx % H;                  // H=1: folds away
  int s = col[e], r = rid[e];
  float lg = aS[s * H + hd] + aD[r * H + hd];
  lg = fmaxf(lg, 0.2f * lg);                      // leaky_relu
  wbuf[idx] = __expf(lg);                         // no max shift: |lg| bounded
}

// ---- segment softmax + weighted aggregate, one wave per dst row -----------
// Weights precomputed in wbuf (coalesced); den via shuffles; gather 1
// edge/iter, readlane (H=1) / LDS-table (H=8) broadcast, v_fma_mix inner.
template<int H, int HC, int ELU, int SPLIT>
__global__ __launch_bounds__(256) void k_aggregate(const unsigned short* __restrict__ h,
    const float* __restrict__ wbuf,
    const int* __restrict__ rowptr, const int* __restrict__ col,
    const float* __restrict__ bias, float* __restrict__ xout,
    unsigned short* __restrict__ a2out, int N)
{
  constexpr int VEC = HC / 64;            // 4 (HC=256) or 1 (HC=64)
  constexpr int C = HC / H;
  constexpr int CH = (H == 8) ? 8 : 64;   // edges per chunk
  __shared__ float wlds[4][64];           // H=8: per-wave [eo*8+hd] weights
  int wave = threadIdx.x >> 6, lane = threadIdx.x & 63;
  int row = blockIdx.x * 4 + wave;
  if (row >= N) return;
  const int cb = lane * VEC;
  const int hdg = cb / C;                 // gather-phase head of this lane
  int s0 = rowptr[row], s1 = rowptr[row + 1];

  float den = 0.f;
  float acc[VEC];
  #pragma unroll
  for (int v = 0; v < VEC; v++) acc[v] = 0.f;

  for (int base = s0; base < s1; base += CH) {
    int cnt = min(CH, s1 - base);
    // ---- load chunk weights (coalesced) + cols ----
    int eo = (H == 8) ? (lane >> 3) : lane;
    bool valid = eo < cnt;
    int s = col[valid ? (base + eo) : (s1 - 1)];
    float wv = valid ? wbuf[(unsigned)(base * H) + lane] : 0.f;
    float d = wv;
    if constexpr (H == 8) {
      d += __shfl_xor(d, 8); d += __shfl_xor(d, 16); d += __shfl_xor(d, 32);
      wlds[wave][lane] = wv;              // [eo*8+hd]
    } else {
      #pragma unroll
      for (int off = 1; off < 64; off <<= 1) d += __shfl_xor(d, off);
    }
    den += d;                             // H==8: lane holds den[lane&7]
    if (H == 8) {
      asm volatile("s_waitcnt lgkmcnt(0)" ::: "memory");  // wave-local order
    }
    // ---- gather (v_fma_mix inner, 32-bit offsets) ----
    #pragma unroll 4
    for (int j = 0; j < cnt; j++) {
      int sj = __builtin_amdgcn_readlane(s, (H == 8) ? (j * 8) : j);
      float wj;
      if constexpr (H == 8) {
        wj = wlds[wave][j * 8 + hdg];     // 8 banks, 8-lane broadcast each
      } else {
        wj = __builtin_bit_cast(float,
              __builtin_amdgcn_readlane(__builtin_bit_cast(int, wv), j));
      }
      unsigned off = (unsigned)sj * HC + cb;
      if constexpr (VEC == 4) {
        uint2 raw = *(const uint2*)(h + off);
        fma_mix_lo(acc[0], raw.x, wj);
        fma_mix_hi(acc[1], raw.x, wj);
        fma_mix_lo(acc[2], raw.y, wj);
        fma_mix_hi(acc[3], raw.y, wj);
      } else {
        unsigned int raw = h[off];        // zero-extended ushort load
        fma_mix_lo(acc[0], raw, wj);
      }
    }
  }
  if (H == 8) den = __shfl(den, hdg);     // den[h] lives at lane h
  float inv = 1.f / (den + 1e-16f);
  float o[VEC];
  #pragma unroll
  for (int v = 0; v < VEC; v++) {
    float t = acc[v] * inv + bias[cb + v];
    if (ELU) t = t > 0.f ? t : expm1f(t);
    o[v] = t;
  }
  if constexpr (SPLIT) {
    unsigned short hi[4], lo[4];
    #pragma unroll
    for (int v = 0; v < 4; v++) {
      hi[v] = f2bf(o[v]);
      lo[v] = f2bf(o[v] - bf2f(hi[v]));
    }
    size_t b2 = (size_t)row * (2 * HC) + cb;
    *(uint2*)&a2out[b2] = make_uint2((unsigned)hi[0] | ((unsigned)hi[1] << 16),
                                     (unsigned)hi[2] | ((unsigned)hi[3] << 16));
    *(uint2*)&a2out[b2 + HC] = make_uint2((unsigned)lo[0] | ((unsigned)lo[1] << 16),
                                          (unsigned)lo[2] | ((unsigned)lo[3] << 16));
  } else if constexpr (VEC == 4) {
    *(float4*)&xout[(size_t)row * HC + cb] = make_float4(o[0], o[1], o[2], o[3]);
  } else {
    xout[(size_t)row * HC + cb] = o[0];
  }
}

// ------------------------- CSR construction --------------------------------
__global__ void k_init(int* deg, float* pool, unsigned short* A2, int N, int B,
                       int Mpad) {
  int i = blockIdx.x * 256 + threadIdx.x;
  if (i < N) deg[i] = 1;                  // self loop
  if (i < B * 64) pool[i] = 0.f;
  int padn = (Mpad - N) * 512;            // zero stride-512 pad rows of A2
  if (i < padn) A2[(size_t)N * 512 + i] = 0;
}

__global__ void k_deg(const int* __restrict__ ei, int* deg, int E) {
  int e = blockIdx.x * 256 + threadIdx.x;
  if (e < E) atomicAdd(&deg[ei[E + e]], 1);
}

__global__ __launch_bounds__(256) void k_scan1(const int* __restrict__ deg,
                                               int* csum, int N, int chunk) {
  int bid = blockIdx.x, t = threadIdx.x;
  int lo = bid * chunk, hi = min(lo + chunk, N);
  int s = 0;
  for (int i = lo + t; i < hi; i += 256) s += deg[i];
  #pragma unroll
  for (int off = 32; off; off >>= 1) s += __shfl_xor(s, off);
  __shared__ int sh[4];
  if ((t & 63) == 0) sh[t >> 6] = s;
  __syncthreads();
  if (t == 0) csum[bid] = sh[0] + sh[1] + sh[2] + sh[3];
}

// scan2 + per-graph counts (batch sorted -> binary search), one block
__global__ __launch_bounds__(256) void k_scan2(const int* __restrict__ csum,
    int* coff, const int* __restrict__ bat, int* cnt, int N, int B) {
  __shared__ int s[256];
  int t = threadIdx.x;
  int v0 = csum[t];
  s[t] = v0;
  for (int off = 1; off < 256; off <<= 1) {
    __syncthreads();
    int v = (t >= off) ? s[t - off] : 0;
    __syncthreads();
    s[t] += v;
  }
  __syncthreads();
  coff[t] = s[t] - v0;
  if (t < B) {
    int lo0 = 0, hi0 = N;
    while (lo0 < hi0) { int mid = (lo0 + hi0) >> 1; if (bat[mid] < t) lo0 = mid + 1; else hi0 = mid; }
    int lo1 = lo0, hi1 = N;
    while (lo1 < hi1) { int mid = (lo1 + hi1) >> 1; if (bat[mid] < t + 1) lo1 = mid + 1; else hi1 = mid; }
    cnt[t] = lo1 - lo0;
  }
}

__global__ __launch_bounds__(256) void k_scan3(const int* __restrict__ deg,
    const int* __restrict__ coff, int* rowptr, int* cursor, int N, int chunk) {
  __shared__ int s[256];
  int bid = blockIdx.x, t = threadIdx.x;
  int i = bid * chunk + t;
  int v = (t < chunk && i < N) ? deg[i] : 0;
  s[t] = v;
  for (int off = 1; off < 256; off <<= 1) {
    __syncthreads();
    int x = (t >= off) ? s[t - off] : 0;
    __syncthreads();
    s[t] += x;
  }
  __syncthreads();
  int excl = s[t] - v + coff[bid];
  if (t < chunk && i < N) {
    rowptr[i] = excl;
    cursor[i] = excl;
    if (i == N - 1) rowptr[N] = excl + v;
  }
}

__global__ void k_scatter(const int* __restrict__ ei, int* cursor, int* col,
                          int* rid, int E, int N) {
  int idx = blockIdx.x * 256 + threadIdx.x;
  if (idx >= E + N) return;
  int s, d;
  if (idx < E) { s = ei[idx]; d = ei[E + idx]; }
  else         { s = d = idx - E; }
  int pos = atomicAdd(&cursor[d], 1);
  col[pos] = s;
  rid[pos] = d;
}

// ------------------------------ pooling ------------------------------------
__global__ __launch_bounds__(256) void k_pool(const float* __restrict__ xg,
    const int* __restrict__ bat, float* pool, int N) {
  int lane = threadIdx.x & 63, w = threadIdx.x >> 6;
  int base = (blockIdx.x * 4 + w) * 16;
  if (base >= N) return;
  int end = min(base + 16, N);
  float local = 0.f;
  int curb = bat[base];
  for (int n = base; n < end; n++) {
    int b = bat[n];
    if (b != curb) {
      atomicAdd(&pool[curb * 64 + lane], local);
      local = 0.f; curb = b;
    }
    local += xg[(size_t)n * 64 + lane];
  }
  atomicAdd(&pool[curb * 64 + lane], local);
}

__global__ void k_final(const float* __restrict__ pool, const int* __restrict__ cnt,
    const float* __restrict__ Wl, const float* __restrict__ bl,
    float* __restrict__ out, int B) {
  int lane = threadIdx.x;                 // 64 threads
  int c = (lane < B) ? cnt[lane] : 0;
  #pragma unroll
  for (int off = 32; off; off >>= 1) c = max(c, __shfl_xor(c, off));
  float invm = 1.f / (float)c;
  float wl = Wl[lane];
  for (int b = 0; b < B; b++) {
    float ps = pool[b * 64 + lane] * wl;
    #pragma unroll
    for (int off = 32; off; off >>= 1) ps += __shfl_xor(ps, off);
    if (lane == 0) out[b] = ps * invm + bl[0];
  }
}

// ---------------------------------------------------------------------------
extern "C" void kernel_launch(void* const* d_in, const int* in_sizes, int n_in,
                              void* d_out, int out_size, void* d_ws, size_t ws_size,
                              hipStream_t stream)
{
  (void)n_in; (void)ws_size;
  const float* x   = (const float*)d_in[0];
  const int*   ei  = (const int*)d_in[1];
  const int*   bat = (const int*)d_in[2];
  const float* W1  = (const float*)d_in[3];
  const float* as1 = (const float*)d_in[4];
  const float* ad1 = (const float*)d_in[5];
  const float* b1  = (const float*)d_in[6];
  const float* W2  = (const float*)d_in[7];
  const float* as2 = (const float*)d_in[8];
  const float* ad2 = (const float*)d_in[9];
  const float* b2  = (const float*)d_in[10];
  const float* W3  = (const float*)d_in[11];
  const float* as3 = (const float*)d_in[12];
  const float* ad3 = (const float*)d_in[13];
  const float* b3  = (const float*)d_in[14];
  const float* W4  = (const float*)d_in[15];
  const float* as4 = (const float*)d_in[16];
  const float* ad4 = (const float*)d_in[17];
  const float* b4  = (const float*)d_in[18];
  const float* Wl  = (const float*)d_in[19];
  const float* bl  = (const float*)d_in[20];
  float* out = (float*)d_out;

  const int N = in_sizes[0] / 128;
  const int E = in_sizes[1] / 2;
  const int B = out_size;
  const int Mpad = ((N + 127) / 128) * 128;
  const int EN = E + N;

  char* p = (char*)d_ws;
  auto alloc = [&](size_t bytes) -> void* {
    void* r = (void*)p;
    p += ((bytes + 255) & ~(size_t)255);
    return r;
  };
  unsigned short* A2 = (unsigned short*)alloc((size_t)Mpad * 512 * 2);
  unsigned short* hbuf = (unsigned short*)alloc((size_t)N * 256 * 2);
  unsigned short* w2t1 = (unsigned short*)alloc((size_t)256 * 512 * 2);
  unsigned short* w2t2 = (unsigned short*)alloc((size_t)256 * 512 * 2);
  unsigned short* w2t3 = (unsigned short*)alloc((size_t)256 * 512 * 2);
  unsigned short* w2t4 = (unsigned short*)alloc((size_t)128 * 512 * 2);
  float* aAll  = (float*)alloc((size_t)N * 22 * 4);
  float* aSb   = aAll;
  float* aDb   = aAll + (size_t)N * 11;
  float* wbuf  = (float*)alloc((size_t)EN * 8 * 4);
  int*   deg   = (int*)alloc((size_t)N * 4);
  int*   rowptr= (int*)alloc((size_t)(N + 1) * 4);
  int*   cursor= (int*)alloc((size_t)N * 4);
  int*   col   = (int*)alloc((size_t)EN * 4);
  int*   rid   = (int*)alloc((size_t)EN * 4);
  int*   csum  = (int*)alloc(256 * 4);
  int*   coff  = (int*)alloc(256 * 4);
  float* pool  = (float*)alloc((size_t)B * 64 * 4);
  int*   cnt   = (int*)alloc((size_t)B * 4);
  float* xpool = (float*)A2;              // layer-4 output reuses A2 (fp32 [N,64])

  const int chunk = (N + 255) / 256;
  dim3 T(256);

  // ---- CSR build + init ----
  k_init<<<dim3((N + 255) / 256), T, 0, stream>>>(deg, pool, A2, N, B, Mpad);
  k_deg<<<dim3((E + 255) / 256), T, 0, stream>>>(ei, deg, E);
  k_scan1<<<dim3(256), T, 0, stream>>>(deg, csum, N, chunk);
  k_scan2<<<dim3(1), T, 0, stream>>>(csum, coff, bat, cnt, N, B);
  k_scan3<<<dim3(256), T, 0, stream>>>(deg, coff, rowptr, cursor, N, chunk);
  k_scatter<<<dim3((EN + 255) / 256), T, 0, stream>>>(ei, cursor, col, rid, E, N);
  hipMemsetAsync(aAll, 0, (size_t)N * 22 * 4, stream);

  // ---- weight + input packing ----
  k_packX<<<dim3(Mpad / 8), T, 0, stream>>>(x, A2, N, Mpad);
  k_packW_all<<<dim3(1536), T, 0, stream>>>(W1, W2, W3, W4, w2t1, w2t2, w2t3, w2t4);

  dim3 nwav((N + 3) / 4);
  dim3 g2(Mpad / 64, 2), g1(Mpad / 64, 1);
  dim3 gw8((EN * 8 + 255) / 256), gw1((EN + 255) / 256);

  // per-layer alpha buffers inside the arena
  float* aS1 = aSb;                 float* aD1 = aDb;                 // N*8
  float* aS2 = aSb + (size_t)N * 8; float* aD2 = aDb + (size_t)N * 8; // N
  float* aS3 = aSb + (size_t)N * 9; float* aD3 = aDb + (size_t)N * 9; // N
  float* aS4 = aSb + (size_t)N * 10;float* aD4 = aDb + (size_t)N * 10;// N

  // ---- layer 1: [N,128]@[128,256], H=8, ELU ----
  k_gemm_mfma<8><<<g2, T, 0, stream>>>(A2, w2t1, hbuf, as1, ad1, aS1, aD1, N, 128, 256);
  k_wcomp<8><<<gw8, T, 0, stream>>>(aS1, aD1, col, rid, wbuf, EN * 8);
  k_aggregate<8, 256, 1, 1><<<nwav, T, 0, stream>>>(hbuf, wbuf, rowptr, col, b1,
                                                    nullptr, A2, N);
  // ---- layer 2 ----
  k_gemm_mfma<1><<<g2, T, 0, stream>>>(A2, w2t2, hbuf, as2, ad2, aS2, aD2, N, 256, 256);
  k_wcomp<1><<<gw1, T, 0, stream>>>(aS2, aD2, col, rid, wbuf, EN);
  k_aggregate<1, 256, 1, 1><<<nwav, T, 0, stream>>>(hbuf, wbuf, rowptr, col, b2,
                                                    nullptr, A2, N);
  // ---- layer 3 ----
  k_gemm_mfma<1><<<g2, T, 0, stream>>>(A2, w2t3, hbuf, as3, ad3, aS3, aD3, N, 256, 256);
  k_wcomp<1><<<gw1, T, 0, stream>>>(aS3, aD3, col, rid, wbuf, EN);
  k_aggregate<1, 256, 1, 1><<<nwav, T, 0, stream>>>(hbuf, wbuf, rowptr, col, b3,
                                                    nullptr, A2, N);
  // ---- layer 4: [N,256]@[256,64], H=1, no ELU ----
  k_gemm_mfma<1><<<g1, T, 0, stream>>>(A2, w2t4, hbuf, as4, ad4, aS4, aD4, N, 256, 64);
  k_wcomp<1><<<gw1, T, 0, stream>>>(aS4, aD4, col, rid, wbuf, EN);
  k_aggregate<1, 64, 0, 0><<<nwav, T, 0, stream>>>(hbuf, wbuf, rowptr, col, b4,
                                                   xpool, nullptr, N);

  // ---- pooling + final linear ----
  k_pool<<<dim3((N + 63) / 64), T, 0, stream>>>(xpool, bat, pool, N);
  k_final<<<dim3(1), dim3(64), 0, stream>>>(pool, cnt, Wl, bl, out, B);
}

// Round 13
// 419.220 us; speedup vs baseline: 1.1041x; 1.0999x over previous
//
#include <hip/hip_runtime.h>
#include <math.h>

// ---------------------------------------------------------------------------
// GAT 4-layer forward.
// GEMMs: single-term bf16 MFMA (C ~ bf16(A)*bf16(W)) -> fp32 acc; 64x128
// tile; alpha dots fused in epilogue. Error budget: A/W bf16 rounding gives
// ~1e-3 per-h perturbation; measured output response to 2e-3 was 9.8e-4
// (threshold 3.1e-3). h stored fp16.
// Edge weights precomputed edge-parallel (k_wcomp). Aggregation: CSR per-dst
// wave; readlane/LDS broadcast; v_fma_mix inner; 32-bit offsets.
// ---------------------------------------------------------------------------

typedef __attribute__((ext_vector_type(8))) short short8;
typedef __attribute__((ext_vector_type(4))) float f32x4;

__device__ __forceinline__ unsigned short f2bf(float f) {
  unsigned int u = __builtin_bit_cast(unsigned int, f);
  unsigned int r = u + 0x7FFFu + ((u >> 16) & 1u);   // RNE
  return (unsigned short)(r >> 16);
}
__device__ __forceinline__ float bf2f(unsigned short h) {
  unsigned int u = ((unsigned int)h) << 16;
  return __builtin_bit_cast(float, u);
}
__device__ __forceinline__ unsigned short f2h(float f) {
  _Float16 h = (_Float16)f;
  return __builtin_bit_cast(unsigned short, h);
}
__device__ __forceinline__ float h2f(unsigned short u) {
  return (float)__builtin_bit_cast(_Float16, u);
}

// acc += (f16 lo/hi half of packed) * w   -- single VALU op each
__device__ __forceinline__ void fma_mix_lo(float& acc, unsigned int packed, float w) {
  asm("v_fma_mix_f32 %0, %1, %2, %0 op_sel_hi:[1,0,0]"
      : "+v"(acc) : "v"(packed), "v"(w));
}
__device__ __forceinline__ void fma_mix_hi(float& acc, unsigned int packed, float w) {
  asm("v_fma_mix_f32 %0, %1, %2, %0 op_sel:[1,0,0] op_sel_hi:[1,0,0]"
      : "+v"(acc) : "v"(packed), "v"(w));
}

__device__ __forceinline__ void gload16(const unsigned short* g, unsigned short* l) {
  __builtin_amdgcn_global_load_lds(
      (const __attribute__((address_space(1))) void*)g,
      (__attribute__((address_space(3))) void*)l, 16, 0, 0);
}

// ---------------- MFMA GEMM: C[M,Nc] = A[M,K] @ Wt[Ncpad,K]^T --------------
// 64x128 tile, 4 waves (2 row-halves x 2 col-halves), LDS 24 KB.
template<int H>
__global__ __launch_bounds__(256) void k_gemm_mfma(
    const unsigned short* __restrict__ A2, const unsigned short* __restrict__ Wt,
    unsigned short* __restrict__ C, const float* __restrict__ avec_s,
    const float* __restrict__ avec_d, float* __restrict__ outS,
    float* __restrict__ outD, int M, int Kb, int Nc)
{
  __shared__ unsigned short lds[12288];     // 24 KB: As[64][64] | Bs[128][64]
  unsigned short* As = lds;
  unsigned short* Bs = lds + 4096;
  const int tid = threadIdx.x;
  const int w = tid >> 6, l = tid & 63;
  const int row0 = blockIdx.x * 64, col0 = blockIdx.y * 128;
  const int wr = w >> 1, wc = w & 1;
  const int fr = l & 15, kg = l >> 4;
  const int xr = (fr & 7) << 4;                   // read-side XOR (bytes)
  const int sK = Kb;                              // single bf16 panel
  const int csrc = 8 * ((l & 7) ^ ((l >> 3) & 7));    // pre-swizzled src col
  const int lrow = l >> 3;                        // 8 lanes per row

  f32x4 acc[2][4];
  #pragma unroll
  for (int i = 0; i < 2; i++)
    #pragma unroll
    for (int j = 0; j < 4; j++) acc[i][j] = (f32x4){0.f, 0.f, 0.f, 0.f};

  for (int kp = 0; kp < sK; kp += 64) {
    #pragma unroll
    for (int i = 0; i < 2; i++) {               // A: 8 KB
      int q = w * 2 + i;
      gload16(&A2[(size_t)(row0 + q * 8 + lrow) * sK + (kp + csrc)], &As[q * 512]);
    }
    #pragma unroll
    for (int i = 0; i < 4; i++) {               // B: 16 KB
      int q = w * 4 + i;
      gload16(&Wt[(size_t)(col0 + q * 8 + lrow) * sK + (kp + csrc)], &Bs[q * 512]);
    }
    __syncthreads();
    #pragma unroll
    for (int kk = 0; kk < 2; kk++) {
      short8 a[2], b[4];
      #pragma unroll
      for (int mi = 0; mi < 2; mi++) {
        int r = wr * 32 + mi * 16 + fr;
        int off = r * 128 + ((kk * 64 + kg * 16) ^ xr);
        a[mi] = *(const short8*)((const char*)As + off);
      }
      #pragma unroll
      for (int ni = 0; ni < 4; ni++) {
        int c = wc * 64 + ni * 16 + fr;
        int off = c * 128 + ((kk * 64 + kg * 16) ^ xr);
        b[ni] = *(const short8*)((const char*)Bs + off);
      }
      #pragma unroll
      for (int mi = 0; mi < 2; mi++)
        #pragma unroll
        for (int ni = 0; ni < 4; ni++)
          acc[mi][ni] = __builtin_amdgcn_mfma_f32_16x16x32_bf16(
              a[mi], b[ni], acc[mi][ni], 0, 0, 0);
    }
    __syncthreads();
  }

  // ---- epilogue: acc -> swizzled LDS C-tile 64x128 fp16 ----
  #pragma unroll
  for (int mi = 0; mi < 2; mi++)
    #pragma unroll
    for (int ni = 0; ni < 4; ni++)
      #pragma unroll
      for (int rr = 0; rr < 4; rr++) {
        int row = wr * 32 + mi * 16 + kg * 4 + rr;
        int c = wc * 64 + ni * 16 + fr;
        int sc = c ^ (((row >> 1) & 7) << 3);
        lds[row * 128 + sc] = f2h(acc[mi][ni][rr]);
      }
  __syncthreads();

  // ---- coalesced store + fused alpha ----
  constexpr int RW = (H == 8) ? 4 : 16;
  const int Ch = Nc / H;
  const int rbase = tid >> 4;                     // 0..15
  const int cc = tid & 15;
  const int c0 = cc * 8;
  const int gc0 = col0 + c0;
  float as8[8], ad8[8];
  #pragma unroll
  for (int j = 0; j < 8; j++) {
    bool ok = (gc0 + j) < Nc;
    as8[j] = ok ? avec_s[gc0 + j] : 0.f;
    ad8[j] = ok ? avec_d[gc0 + j] : 0.f;
  }
  #pragma unroll
  for (int i = 0; i < 4; i++) {
    int row = rbase + i * 16;
    int gr = row0 + row;
    int scc = c0 ^ (((row >> 1) & 7) << 3);
    short8 cv = *(const short8*)&lds[row * 128 + scc];
    if (gr < M && gc0 < Nc)
      *(short8*)&C[(size_t)gr * Nc + gc0] = cv;
    float ps = 0.f, pd = 0.f;
    #pragma unroll
    for (int j = 0; j < 8; j++) {
      float cf = h2f((unsigned short)cv[j]);
      ps = fmaf(cf, as8[j], ps);
      pd = fmaf(cf, ad8[j], pd);
    }
    #pragma unroll
    for (int off = 1; off < RW; off <<= 1) {
      ps += __shfl_xor(ps, off);
      pd += __shfl_xor(pd, off);
    }
    if ((tid & (RW - 1)) == 0 && gr < M) {
      int head = gc0 / Ch;                        // 0-add on OOB pad cols
      atomicAdd(&outS[gr * H + head], ps);
      atomicAdd(&outD[gr * H + head], pd);
    }
  }
}

// ---------------- pack layer-1 input: x fp32 [N,128] -> A2 bf16 [Mpad,128] -
__global__ __launch_bounds__(256) void k_packX(const float* __restrict__ x,
    unsigned short* __restrict__ A2, int N, int Mpad)
{
  int row = blockIdx.x * 8 + (threadIdx.x >> 5);
  int c = (threadIdx.x & 31) * 4;
  if (row >= Mpad) return;
  float4 v = make_float4(0.f, 0.f, 0.f, 0.f);
  if (row < N) v = *(const float4*)&x[(size_t)row * 128 + c];
  unsigned short h0 = f2bf(v.x), h1 = f2bf(v.y), h2 = f2bf(v.z), h3 = f2bf(v.w);
  *(uint2*)&A2[(size_t)row * 128 + c] =
      make_uint2((unsigned)h0 | ((unsigned)h1 << 16),
                 (unsigned)h2 | ((unsigned)h3 << 16));
}

// -------- pack all W fp32 -> bf16 [NCPAD,K] (transposed), one kernel -------
__device__ __forceinline__ void packW_one(const float* __restrict__ W,
    unsigned short* __restrict__ Wt, int K, int NC, int idx)
{
  int c = idx / K, k = idx % K;
  unsigned short o = 0;
  if (c < NC) o = f2bf(W[(size_t)k * NC + c]);
  Wt[(size_t)c * K + k] = o;
}

__global__ void k_packW_all(const float* __restrict__ W1, const float* __restrict__ W2,
    const float* __restrict__ W3, const float* __restrict__ W4,
    unsigned short* __restrict__ t1, unsigned short* __restrict__ t2,
    unsigned short* __restrict__ t3, unsigned short* __restrict__ t4)
{
  int idx = blockIdx.x * 256 + threadIdx.x;
  if (idx < 32768)            packW_one(W1, t1, 128, 256, idx);
  else if (idx < 98304)       packW_one(W2, t2, 256, 256, idx - 32768);
  else if (idx < 163840)      packW_one(W3, t3, 256, 256, idx - 98304);
  else if (idx < 196608)      packW_one(W4, t4, 256,  64, idx - 163840);
}

// ---- edge-parallel weight precompute: wbuf[e*H+h] = exp(leaky(aS+aD)) -----
template<int H>
__global__ void k_wcomp(const float* __restrict__ aS, const float* __restrict__ aD,
    const int* __restrict__ col, const int* __restrict__ rid,
    float* __restrict__ wbuf, int M)
{
  int idx = blockIdx.x * 256 + threadIdx.x;
  if (idx >= M) return;
  int e = idx / H, hd = idx % H;                  // H=1: folds away
  int s = col[e], r = rid[e];
  float lg = aS[s * H + hd] + aD[r * H + hd];
  lg = fmaxf(lg, 0.2f * lg);                      // leaky_relu
  wbuf[idx] = __expf(lg);                         // no max shift: |lg| bounded
}

// ---- segment softmax + weighted aggregate, one wave per dst row -----------
// Weights precomputed in wbuf (coalesced); den via shuffles; gather 1
// edge/iter, readlane (H=1) / LDS-table (H=8) broadcast, v_fma_mix inner.
// SPLIT=1: write bf16 into a2out (row stride HC) for next GEMM.
template<int H, int HC, int ELU, int SPLIT>
__global__ __launch_bounds__(256) void k_aggregate(const unsigned short* __restrict__ h,
    const float* __restrict__ wbuf,
    const int* __restrict__ rowptr, const int* __restrict__ col,
    const float* __restrict__ bias, float* __restrict__ xout,
    unsigned short* __restrict__ a2out, int N)
{
  constexpr int VEC = HC / 64;            // 4 (HC=256) or 1 (HC=64)
  constexpr int C = HC / H;
  constexpr int CH = (H == 8) ? 8 : 64;   // edges per chunk
  __shared__ float wlds[4][64];           // H=8: per-wave [eo*8+hd] weights
  int wave = threadIdx.x >> 6, lane = threadIdx.x & 63;
  int row = blockIdx.x * 4 + wave;
  if (row >= N) return;
  const int cb = lane * VEC;
  const int hdg = cb / C;                 // gather-phase head of this lane
  int s0 = rowptr[row], s1 = rowptr[row + 1];

  float den = 0.f;
  float acc[VEC];
  #pragma unroll
  for (int v = 0; v < VEC; v++) acc[v] = 0.f;

  for (int base = s0; base < s1; base += CH) {
    int cnt = min(CH, s1 - base);
    // ---- load chunk weights (coalesced) + cols ----
    int eo = (H == 8) ? (lane >> 3) : lane;
    bool valid = eo < cnt;
    int s = col[valid ? (base + eo) : (s1 - 1)];
    float wv = valid ? wbuf[(unsigned)(base * H) + lane] : 0.f;
    float d = wv;
    if constexpr (H == 8) {
      d += __shfl_xor(d, 8); d += __shfl_xor(d, 16); d += __shfl_xor(d, 32);
      wlds[wave][lane] = wv;              // [eo*8+hd]
    } else {
      #pragma unroll
      for (int off = 1; off < 64; off <<= 1) d += __shfl_xor(d, off);
    }
    den += d;                             // H==8: lane holds den[lane&7]
    if (H == 8) {
      asm volatile("s_waitcnt lgkmcnt(0)" ::: "memory");  // wave-local order
    }
    // ---- gather (v_fma_mix inner, 32-bit offsets) ----
    #pragma unroll 4
    for (int j = 0; j < cnt; j++) {
      int sj = __builtin_amdgcn_readlane(s, (H == 8) ? (j * 8) : j);
      float wj;
      if constexpr (H == 8) {
        wj = wlds[wave][j * 8 + hdg];     // 8 banks, 8-lane broadcast each
      } else {
        wj = __builtin_bit_cast(float,
              __builtin_amdgcn_readlane(__builtin_bit_cast(int, wv), j));
      }
      unsigned off = (unsigned)sj * HC + cb;
      if constexpr (VEC == 4) {
        uint2 raw = *(const uint2*)(h + off);
        fma_mix_lo(acc[0], raw.x, wj);
        fma_mix_hi(acc[1], raw.x, wj);
        fma_mix_lo(acc[2], raw.y, wj);
        fma_mix_hi(acc[3], raw.y, wj);
      } else {
        unsigned int raw = h[off];        // zero-extended ushort load
        fma_mix_lo(acc[0], raw, wj);
      }
    }
  }
  if (H == 8) den = __shfl(den, hdg);     // den[h] lives at lane h
  float inv = 1.f / (den + 1e-16f);
  float o[VEC];
  #pragma unroll
  for (int v = 0; v < VEC; v++) {
    float t = acc[v] * inv + bias[cb + v];
    if (ELU) t = t > 0.f ? t : expm1f(t);
    o[v] = t;
  }
  if constexpr (SPLIT) {
    unsigned short hi[4];
    #pragma unroll
    for (int v = 0; v < 4; v++) hi[v] = f2bf(o[v]);
    *(uint2*)&a2out[(size_t)row * HC + cb] =
        make_uint2((unsigned)hi[0] | ((unsigned)hi[1] << 16),
                   (unsigned)hi[2] | ((unsigned)hi[3] << 16));
  } else if constexpr (VEC == 4) {
    *(float4*)&xout[(size_t)row * HC + cb] = make_float4(o[0], o[1], o[2], o[3]);
  } else {
    xout[(size_t)row * HC + cb] = o[0];
  }
}

// ------------------------- CSR construction --------------------------------
__global__ void k_init(int* deg, float* pool, unsigned short* A2, int N, int B,
                       int Mpad) {
  int i = blockIdx.x * 256 + threadIdx.x;
  if (i < N) deg[i] = 1;                  // self loop
  if (i < B * 64) pool[i] = 0.f;
  int padn = (Mpad - N) * 256;            // zero stride-256 pad rows of A2
  if (i < padn) A2[(size_t)N * 256 + i] = 0;
}

__global__ void k_deg(const int* __restrict__ ei, int* deg, int E) {
  int e = blockIdx.x * 256 + threadIdx.x;
  if (e < E) atomicAdd(&deg[ei[E + e]], 1);
}

__global__ __launch_bounds__(256) void k_scan1(const int* __restrict__ deg,
                                               int* csum, int N, int chunk) {
  int bid = blockIdx.x, t = threadIdx.x;
  int lo = bid * chunk, hi = min(lo + chunk, N);
  int s = 0;
  for (int i = lo + t; i < hi; i += 256) s += deg[i];
  #pragma unroll
  for (int off = 32; off; off >>= 1) s += __shfl_xor(s, off);
  __shared__ int sh[4];
  if ((t & 63) == 0) sh[t >> 6] = s;
  __syncthreads();
  if (t == 0) csum[bid] = sh[0] + sh[1] + sh[2] + sh[3];
}

// scan2 + per-graph counts (batch sorted -> binary search), one block
__global__ __launch_bounds__(256) void k_scan2(const int* __restrict__ csum,
    int* coff, const int* __restrict__ bat, int* cnt, int N, int B) {
  __shared__ int s[256];
  int t = threadIdx.x;
  int v0 = csum[t];
  s[t] = v0;
  for (int off = 1; off < 256; off <<= 1) {
    __syncthreads();
    int v = (t >= off) ? s[t - off] : 0;
    __syncthreads();
    s[t] += v;
  }
  __syncthreads();
  coff[t] = s[t] - v0;
  if (t < B) {
    int lo0 = 0, hi0 = N;
    while (lo0 < hi0) { int mid = (lo0 + hi0) >> 1; if (bat[mid] < t) lo0 = mid + 1; else hi0 = mid; }
    int lo1 = lo0, hi1 = N;
    while (lo1 < hi1) { int mid = (lo1 + hi1) >> 1; if (bat[mid] < t + 1) lo1 = mid + 1; else hi1 = mid; }
    cnt[t] = lo1 - lo0;
  }
}

__global__ __launch_bounds__(256) void k_scan3(const int* __restrict__ deg,
    const int* __restrict__ coff, int* rowptr, int* cursor, int N, int chunk) {
  __shared__ int s[256];
  int bid = blockIdx.x, t = threadIdx.x;
  int i = bid * chunk + t;
  int v = (t < chunk && i < N) ? deg[i] : 0;
  s[t] = v;
  for (int off = 1; off < 256; off <<= 1) {
    __syncthreads();
    int x = (t >= off) ? s[t - off] : 0;
    __syncthreads();
    s[t] += x;
  }
  __syncthreads();
  int excl = s[t] - v + coff[bid];
  if (t < chunk && i < N) {
    rowptr[i] = excl;
    cursor[i] = excl;
    if (i == N - 1) rowptr[N] = excl + v;
  }
}

__global__ void k_scatter(const int* __restrict__ ei, int* cursor, int* col,
                          int* rid, int E, int N) {
  int idx = blockIdx.x * 256 + threadIdx.x;
  if (idx >= E + N) return;
  int s, d;
  if (idx < E) { s = ei[idx]; d = ei[E + idx]; }
  else         { s = d = idx - E; }
  int pos = atomicAdd(&cursor[d], 1);
  col[pos] = s;
  rid[pos] = d;
}

// ------------------------------ pooling ------------------------------------
__global__ __launch_bounds__(256) void k_pool(const float* __restrict__ xg,
    const int* __restrict__ bat, float* pool, int N) {
  int lane = threadIdx.x & 63, w = threadIdx.x >> 6;
  int base = (blockIdx.x * 4 + w) * 16;
  if (base >= N) return;
  int end = min(base + 16, N);
  float local = 0.f;
  int curb = bat[base];
  for (int n = base; n < end; n++) {
    int b = bat[n];
    if (b != curb) {
      atomicAdd(&pool[curb * 64 + lane], local);
      local = 0.f; curb = b;
    }
    local += xg[(size_t)n * 64 + lane];
  }
  atomicAdd(&pool[curb * 64 + lane], local);
}

__global__ void k_final(const float* __restrict__ pool, const int* __restrict__ cnt,
    const float* __restrict__ Wl, const float* __restrict__ bl,
    float* __restrict__ out, int B) {
  int lane = threadIdx.x;                 // 64 threads
  int c = (lane < B) ? cnt[lane] : 0;
  #pragma unroll
  for (int off = 32; off; off >>= 1) c = max(c, __shfl_xor(c, off));
  float invm = 1.f / (float)c;
  float wl = Wl[lane];
  for (int b = 0; b < B; b++) {
    float ps = pool[b * 64 + lane] * wl;
    #pragma unroll
    for (int off = 32; off; off >>= 1) ps += __shfl_xor(ps, off);
    if (lane == 0) out[b] = ps * invm + bl[0];
  }
}

// ---------------------------------------------------------------------------
extern "C" void kernel_launch(void* const* d_in, const int* in_sizes, int n_in,
                              void* d_out, int out_size, void* d_ws, size_t ws_size,
                              hipStream_t stream)
{
  (void)n_in; (void)ws_size;
  const float* x   = (const float*)d_in[0];
  const int*   ei  = (const int*)d_in[1];
  const int*   bat = (const int*)d_in[2];
  const float* W1  = (const float*)d_in[3];
  const float* as1 = (const float*)d_in[4];
  const float* ad1 = (const float*)d_in[5];
  const float* b1  = (const float*)d_in[6];
  const float* W2  = (const float*)d_in[7];
  const float* as2 = (const float*)d_in[8];
  const float* ad2 = (const float*)d_in[9];
  const float* b2  = (const float*)d_in[10];
  const float* W3  = (const float*)d_in[11];
  const float* as3 = (const float*)d_in[12];
  const float* ad3 = (const float*)d_in[13];
  const float* b3  = (const float*)d_in[14];
  const float* W4  = (const float*)d_in[15];
  const float* as4 = (const float*)d_in[16];
  const float* ad4 = (const float*)d_in[17];
  const float* b4  = (const float*)d_in[18];
  const float* Wl  = (const float*)d_in[19];
  const float* bl  = (const float*)d_in[20];
  float* out = (float*)d_out;

  const int N = in_sizes[0] / 128;
  const int E = in_sizes[1] / 2;
  const int B = out_size;
  const int Mpad = ((N + 127) / 128) * 128;
  const int EN = E + N;

  char* p = (char*)d_ws;
  auto alloc = [&](size_t bytes) -> void* {
    void* r = (void*)p;
    p += ((bytes + 255) & ~(size_t)255);
    return r;
  };
  unsigned short* A2 = (unsigned short*)alloc((size_t)Mpad * 256 * 2);
  unsigned short* hbuf = (unsigned short*)alloc((size_t)N * 256 * 2);
  unsigned short* w2t1 = (unsigned short*)alloc((size_t)256 * 128 * 2);
  unsigned short* w2t2 = (unsigned short*)alloc((size_t)256 * 256 * 2);
  unsigned short* w2t3 = (unsigned short*)alloc((size_t)256 * 256 * 2);
  unsigned short* w2t4 = (unsigned short*)alloc((size_t)128 * 256 * 2);
  float* aAll  = (float*)alloc((size_t)N * 22 * 4);
  float* aSb   = aAll;
  float* aDb   = aAll + (size_t)N * 11;
  float* wbuf  = (float*)alloc((size_t)EN * 8 * 4);
  int*   deg   = (int*)alloc((size_t)N * 4);
  int*   rowptr= (int*)alloc((size_t)(N + 1) * 4);
  int*   cursor= (int*)alloc((size_t)N * 4);
  int*   col   = (int*)alloc((size_t)EN * 4);
  int*   rid   = (int*)alloc((size_t)EN * 4);
  int*   csum  = (int*)alloc(256 * 4);
  int*   coff  = (int*)alloc(256 * 4);
  float* pool  = (float*)alloc((size_t)B * 64 * 4);
  int*   cnt   = (int*)alloc((size_t)B * 4);
  float* xpool = (float*)A2;              // layer-4 output reuses A2 (fp32 [N,64])

  const int chunk = (N + 255) / 256;
  dim3 T(256);

  // ---- CSR build + init ----
  k_init<<<dim3((N + 255) / 256), T, 0, stream>>>(deg, pool, A2, N, B, Mpad);
  k_deg<<<dim3((E + 255) / 256), T, 0, stream>>>(ei, deg, E);
  k_scan1<<<dim3(256), T, 0, stream>>>(deg, csum, N, chunk);
  k_scan2<<<dim3(1), T, 0, stream>>>(csum, coff, bat, cnt, N, B);
  k_scan3<<<dim3(256), T, 0, stream>>>(deg, coff, rowptr, cursor, N, chunk);
  k_scatter<<<dim3((EN + 255) / 256), T, 0, stream>>>(ei, cursor, col, rid, E, N);
  hipMemsetAsync(aAll, 0, (size_t)N * 22 * 4, stream);

  // ---- weight + input packing ----
  k_packX<<<dim3(Mpad / 8), T, 0, stream>>>(x, A2, N, Mpad);
  k_packW_all<<<dim3(768), T, 0, stream>>>(W1, W2, W3, W4, w2t1, w2t2, w2t3, w2t4);

  dim3 nwav((N + 3) / 4);
  dim3 g2(Mpad / 64, 2), g1(Mpad / 64, 1);
  dim3 gw8((EN * 8 + 255) / 256), gw1((EN + 255) / 256);

  // per-layer alpha buffers inside the arena
  float* aS1 = aSb;                 float* aD1 = aDb;                 // N*8
  float* aS2 = aSb + (size_t)N * 8; float* aD2 = aDb + (size_t)N * 8; // N
  float* aS3 = aSb + (size_t)N * 9; float* aD3 = aDb + (size_t)N * 9; // N
  float* aS4 = aSb + (size_t)N * 10;float* aD4 = aDb + (size_t)N * 10;// N

  // ---- layer 1: [N,128]@[128,256], H=8, ELU ----
  k_gemm_mfma<8><<<g2, T, 0, stream>>>(A2, w2t1, hbuf, as1, ad1, aS1, aD1, N, 128, 256);
  k_wcomp<8><<<gw8, T, 0, stream>>>(aS1, aD1, col, rid, wbuf, EN * 8);
  k_aggregate<8, 256, 1, 1><<<nwav, T, 0, stream>>>(hbuf, wbuf, rowptr, col, b1,
                                                    nullptr, A2, N);
  // ---- layer 2 ----
  k_gemm_mfma<1><<<g2, T, 0, stream>>>(A2, w2t2, hbuf, as2, ad2, aS2, aD2, N, 256, 256);
  k_wcomp<1><<<gw1, T, 0, stream>>>(aS2, aD2, col, rid, wbuf, EN);
  k_aggregate<1, 256, 1, 1><<<nwav, T, 0, stream>>>(hbuf, wbuf, rowptr, col, b2,
                                                    nullptr, A2, N);
  // ---- layer 3 ----
  k_gemm_mfma<1><<<g2, T, 0, stream>>>(A2, w2t3, hbuf, as3, ad3, aS3, aD3, N, 256, 256);
  k_wcomp<1><<<gw1, T, 0, stream>>>(aS3, aD3, col, rid, wbuf, EN);
  k_aggregate<1, 256, 1, 1><<<nwav, T, 0, stream>>>(hbuf, wbuf, rowptr, col, b3,
                                                    nullptr, A2, N);
  // ---- layer 4: [N,256]@[256,64], H=1, no ELU ----
  k_gemm_mfma<1><<<g1, T, 0, stream>>>(A2, w2t4, hbuf, as4, ad4, aS4, aD4, N, 256, 64);
  k_wcomp<1><<<gw1, T, 0, stream>>>(aS4, aD4, col, rid, wbuf, EN);
  k_aggregate<1, 64, 0, 0><<<nwav, T, 0, stream>>>(hbuf, wbuf, rowptr, col, b4,
                                                   xpool, nullptr, N);

  // ---- pooling + final linear ----
  k_pool<<<dim3((N + 63) / 64), T, 0, stream>>>(xpool, bat, pool, N);
  k_final<<<dim3(1), dim3(64), 0, stream>>>(pool, cnt, Wl, bl, out, B);
}

// Round 15
// 386.799 us; speedup vs baseline: 1.1967x; 1.0838x over previous
//
#include <hip/hip_runtime.h>
#include <math.h>

// ---------------------------------------------------------------------------
// GAT 4-layer forward.
// GEMMs: single-term bf16 MFMA -> fp32 acc; 64x128 tile; alpha dots fused in
// epilogue. h stored fp16. Edge weights precomputed edge-parallel (k_wcomp).
// Aggregation: ONE WAVE PER ROW (64-thread blocks -> per-row retirement, no
// LDS for H=1/HC=256); HC=64 path gathers 4 edges/iter via LDS tables.
// R14 bug fixed: k_pool grid was (N+1023)/1024, must be (N+63)/64.
// ---------------------------------------------------------------------------

typedef __attribute__((ext_vector_type(8))) short short8;
typedef __attribute__((ext_vector_type(4))) float f32x4;

__device__ __forceinline__ unsigned short f2bf(float f) {
  unsigned int u = __builtin_bit_cast(unsigned int, f);
  unsigned int r = u + 0x7FFFu + ((u >> 16) & 1u);   // RNE
  return (unsigned short)(r >> 16);
}
__device__ __forceinline__ float bf2f(unsigned short h) {
  unsigned int u = ((unsigned int)h) << 16;
  return __builtin_bit_cast(float, u);
}
__device__ __forceinline__ unsigned short f2h(float f) {
  _Float16 h = (_Float16)f;
  return __builtin_bit_cast(unsigned short, h);
}
__device__ __forceinline__ float h2f(unsigned short u) {
  return (float)__builtin_bit_cast(_Float16, u);
}

// acc += (f16 lo/hi half of packed) * w   -- single VALU op each
__device__ __forceinline__ void fma_mix_lo(float& acc, unsigned int packed, float w) {
  asm("v_fma_mix_f32 %0, %1, %2, %0 op_sel_hi:[1,0,0]"
      : "+v"(acc) : "v"(packed), "v"(w));
}
__device__ __forceinline__ void fma_mix_hi(float& acc, unsigned int packed, float w) {
  asm("v_fma_mix_f32 %0, %1, %2, %0 op_sel:[1,0,0] op_sel_hi:[1,0,0]"
      : "+v"(acc) : "v"(packed), "v"(w));
}

__device__ __forceinline__ void gload16(const unsigned short* g, unsigned short* l) {
  __builtin_amdgcn_global_load_lds(
      (const __attribute__((address_space(1))) void*)g,
      (__attribute__((address_space(3))) void*)l, 16, 0, 0);
}

// ---------------- MFMA GEMM: C[M,Nc] = A[M,K] @ Wt[Ncpad,K]^T --------------
// 64x128 tile, 4 waves (2 row-halves x 2 col-halves), LDS 24 KB.
template<int H>
__global__ __launch_bounds__(256) void k_gemm_mfma(
    const unsigned short* __restrict__ A2, const unsigned short* __restrict__ Wt,
    unsigned short* __restrict__ C, const float* __restrict__ avec_s,
    const float* __restrict__ avec_d, float* __restrict__ outS,
    float* __restrict__ outD, int M, int Kb, int Nc)
{
  __shared__ unsigned short lds[12288];     // 24 KB: As[64][64] | Bs[128][64]
  unsigned short* As = lds;
  unsigned short* Bs = lds + 4096;
  const int tid = threadIdx.x;
  const int w = tid >> 6, l = tid & 63;
  const int row0 = blockIdx.x * 64, col0 = blockIdx.y * 128;
  const int wr = w >> 1, wc = w & 1;
  const int fr = l & 15, kg = l >> 4;
  const int xr = (fr & 7) << 4;                   // read-side XOR (bytes)
  const int sK = Kb;                              // single bf16 panel
  const int csrc = 8 * ((l & 7) ^ ((l >> 3) & 7));    // pre-swizzled src col
  const int lrow = l >> 3;                        // 8 lanes per row

  f32x4 acc[2][4];
  #pragma unroll
  for (int i = 0; i < 2; i++)
    #pragma unroll
    for (int j = 0; j < 4; j++) acc[i][j] = (f32x4){0.f, 0.f, 0.f, 0.f};

  for (int kp = 0; kp < sK; kp += 64) {
    #pragma unroll
    for (int i = 0; i < 2; i++) {               // A: 8 KB
      int q = w * 2 + i;
      gload16(&A2[(size_t)(row0 + q * 8 + lrow) * sK + (kp + csrc)], &As[q * 512]);
    }
    #pragma unroll
    for (int i = 0; i < 4; i++) {               // B: 16 KB
      int q = w * 4 + i;
      gload16(&Wt[(size_t)(col0 + q * 8 + lrow) * sK + (kp + csrc)], &Bs[q * 512]);
    }
    __syncthreads();
    #pragma unroll
    for (int kk = 0; kk < 2; kk++) {
      short8 a[2], b[4];
      #pragma unroll
      for (int mi = 0; mi < 2; mi++) {
        int r = wr * 32 + mi * 16 + fr;
        int off = r * 128 + ((kk * 64 + kg * 16) ^ xr);
        a[mi] = *(const short8*)((const char*)As + off);
      }
      #pragma unroll
      for (int ni = 0; ni < 4; ni++) {
        int c = wc * 64 + ni * 16 + fr;
        int off = c * 128 + ((kk * 64 + kg * 16) ^ xr);
        b[ni] = *(const short8*)((const char*)Bs + off);
      }
      #pragma unroll
      for (int mi = 0; mi < 2; mi++)
        #pragma unroll
        for (int ni = 0; ni < 4; ni++)
          acc[mi][ni] = __builtin_amdgcn_mfma_f32_16x16x32_bf16(
              a[mi], b[ni], acc[mi][ni], 0, 0, 0);
    }
    __syncthreads();
  }

  // ---- epilogue: acc -> swizzled LDS C-tile 64x128 fp16 ----
  #pragma unroll
  for (int mi = 0; mi < 2; mi++)
    #pragma unroll
    for (int ni = 0; ni < 4; ni++)
      #pragma unroll
      for (int rr = 0; rr < 4; rr++) {
        int row = wr * 32 + mi * 16 + kg * 4 + rr;
        int c = wc * 64 + ni * 16 + fr;
        int sc = c ^ (((row >> 1) & 7) << 3);
        lds[row * 128 + sc] = f2h(acc[mi][ni][rr]);
      }
  __syncthreads();

  // ---- coalesced store + fused alpha ----
  constexpr int RW = (H == 8) ? 4 : 16;
  const int Ch = Nc / H;
  const int rbase = tid >> 4;                     // 0..15
  const int cc = tid & 15;
  const int c0 = cc * 8;
  const int gc0 = col0 + c0;
  float as8[8], ad8[8];
  #pragma unroll
  for (int j = 0; j < 8; j++) {
    bool ok = (gc0 + j) < Nc;
    as8[j] = ok ? avec_s[gc0 + j] : 0.f;
    ad8[j] = ok ? avec_d[gc0 + j] : 0.f;
  }
  #pragma unroll
  for (int i = 0; i < 4; i++) {
    int row = rbase + i * 16;
    int gr = row0 + row;
    int scc = c0 ^ (((row >> 1) & 7) << 3);
    short8 cv = *(const short8*)&lds[row * 128 + scc];
    if (gr < M && gc0 < Nc)
      *(short8*)&C[(size_t)gr * Nc + gc0] = cv;
    float ps = 0.f, pd = 0.f;
    #pragma unroll
    for (int j = 0; j < 8; j++) {
      float cf = h2f((unsigned short)cv[j]);
      ps = fmaf(cf, as8[j], ps);
      pd = fmaf(cf, ad8[j], pd);
    }
    #pragma unroll
    for (int off = 1; off < RW; off <<= 1) {
      ps += __shfl_xor(ps, off);
      pd += __shfl_xor(pd, off);
    }
    if ((tid & (RW - 1)) == 0 && gr < M) {
      int head = gc0 / Ch;                        // 0-add on OOB pad cols
      atomicAdd(&outS[gr * H + head], ps);
      atomicAdd(&outD[gr * H + head], pd);
    }
  }
}

// -------- pack all W fp32 -> bf16 [NCPAD,K] + x fp32 -> bf16 [Mpad,128] ----
__device__ __forceinline__ void packW_one(const float* __restrict__ W,
    unsigned short* __restrict__ Wt, int K, int NC, int idx)
{
  int c = idx / K, k = idx % K;
  unsigned short o = 0;
  if (c < NC) o = f2bf(W[(size_t)k * NC + c]);
  Wt[(size_t)c * K + k] = o;
}

__global__ void k_pack_all(const float* __restrict__ W1, const float* __restrict__ W2,
    const float* __restrict__ W3, const float* __restrict__ W4,
    unsigned short* __restrict__ t1, unsigned short* __restrict__ t2,
    unsigned short* __restrict__ t3, unsigned short* __restrict__ t4,
    const float* __restrict__ x, unsigned short* __restrict__ A2,
    int N, int Mpad)
{
  int idx = blockIdx.x * 256 + threadIdx.x;
  if (idx < 32768)            packW_one(W1, t1, 128, 256, idx);
  else if (idx < 98304)       packW_one(W2, t2, 256, 256, idx - 32768);
  else if (idx < 163840)      packW_one(W3, t3, 256, 256, idx - 98304);
  else if (idx < 196608)      packW_one(W4, t4, 256,  64, idx - 163840);
  else {
    int t = idx - 196608;                        // packX: t in [0, Mpad*32)
    int row = t >> 5;
    if (row >= Mpad) return;
    int c = (t & 31) * 4;
    float4 v = make_float4(0.f, 0.f, 0.f, 0.f);
    if (row < N) v = *(const float4*)&x[(size_t)row * 128 + c];
    unsigned short h0 = f2bf(v.x), h1 = f2bf(v.y), h2 = f2bf(v.z), h3 = f2bf(v.w);
    *(uint2*)&A2[(size_t)row * 128 + c] =
        make_uint2((unsigned)h0 | ((unsigned)h1 << 16),
                   (unsigned)h2 | ((unsigned)h3 << 16));
  }
}

// ---- edge-parallel weight precompute: wbuf[e*H+h] = exp(leaky(aS+aD)) -----
template<int H>
__global__ void k_wcomp(const float* __restrict__ aS, const float* __restrict__ aD,
    const int* __restrict__ col, const int* __restrict__ rid,
    float* __restrict__ wbuf, int M)
{
  int idx = blockIdx.x * 256 + threadIdx.x;
  if (idx >= M) return;
  int e = idx / H, hd = idx % H;                  // H=1: folds away
  int s = col[e], r = rid[e];
  float lg = aS[s * H + hd] + aD[r * H + hd];
  lg = fmaxf(lg, 0.2f * lg);                      // leaky_relu
  wbuf[idx] = __expf(lg);                         // no max shift: |lg| bounded
}

// ---- segment softmax + weighted aggregate, ONE WAVE PER ROW ---------------
// 64-thread blocks: per-row retirement; H=1/HC=256 needs no LDS.
// HC=64: 4 edges/iteration via per-wave LDS weight/col tables.
template<int H, int HC, int ELU, int SPLIT>
__global__ __launch_bounds__(64) void k_aggregate(const unsigned short* __restrict__ h,
    const float* __restrict__ wbuf,
    const int* __restrict__ rowptr, const int* __restrict__ col,
    const float* __restrict__ bias, float* __restrict__ xout,
    unsigned short* __restrict__ a2out, int N)
{
  const int lane = threadIdx.x;
  const int row = blockIdx.x;
  if (row >= N) return;
  int s0 = rowptr[row], s1 = rowptr[row + 1];
  float den = 0.f;

  if constexpr (HC == 256) {
    constexpr int C = HC / H;
    constexpr int CH = (H == 8) ? 8 : 64;
    __shared__ float wlds[(H == 8) ? 64 : 1];
    const int cb = lane * 4;
    const int hdg = cb / C;
    float acc[4] = {0.f, 0.f, 0.f, 0.f};
    for (int base = s0; base < s1; base += CH) {
      int cnt = min(CH, s1 - base);
      int eo = (H == 8) ? (lane >> 3) : lane;
      bool valid = eo < cnt;
      int s = col[valid ? (base + eo) : (s1 - 1)];
      float wv = valid ? wbuf[(unsigned)(base * H) + lane] : 0.f;
      float d = wv;
      if constexpr (H == 8) {
        d += __shfl_xor(d, 8); d += __shfl_xor(d, 16); d += __shfl_xor(d, 32);
        wlds[lane] = wv;                  // [eo*8+hd]
      } else {
        #pragma unroll
        for (int off = 1; off < 64; off <<= 1) d += __shfl_xor(d, off);
      }
      den += d;                           // H==8: lane holds den[lane&7]
      if (H == 8) {
        asm volatile("s_waitcnt lgkmcnt(0)" ::: "memory");  // wave-local order
      }
      #pragma unroll 4
      for (int j = 0; j < cnt; j++) {
        int sj = __builtin_amdgcn_readlane(s, (H == 8) ? (j * 8) : j);
        float wj;
        if constexpr (H == 8) {
          wj = wlds[j * 8 + hdg];
        } else {
          wj = __builtin_bit_cast(float,
                __builtin_amdgcn_readlane(__builtin_bit_cast(int, wv), j));
        }
        unsigned off = (unsigned)sj * HC + cb;
        uint2 raw = *(const uint2*)(h + off);
        fma_mix_lo(acc[0], raw.x, wj);
        fma_mix_hi(acc[1], raw.x, wj);
        fma_mix_lo(acc[2], raw.y, wj);
        fma_mix_hi(acc[3], raw.y, wj);
      }
    }
    if (H == 8) den = __shfl(den, hdg);
    float inv = 1.f / (den + 1e-16f);
    float o[4];
    #pragma unroll
    for (int v = 0; v < 4; v++) {
      float t = acc[v] * inv + bias[cb + v];
      if (ELU) t = t > 0.f ? t : expm1f(t);
      o[v] = t;
    }
    if constexpr (SPLIT) {
      unsigned short hi[4];
      #pragma unroll
      for (int v = 0; v < 4; v++) hi[v] = f2bf(o[v]);
      *(uint2*)&a2out[(size_t)row * HC + cb] =
          make_uint2((unsigned)hi[0] | ((unsigned)hi[1] << 16),
                     (unsigned)hi[2] | ((unsigned)hi[3] << 16));
    } else {
      *(float4*)&xout[(size_t)row * HC + cb] = make_float4(o[0], o[1], o[2], o[3]);
    }
  } else {
    // ---- HC == 64, H == 1: 4 edges/iteration, 16 lanes per edge ----
    __shared__ float wlds[64];
    __shared__ int   slds[64];
    const int cb = (lane & 15) * 4;       // 4 fp16 channels (8 B)
    const int g = lane >> 4;              // edge sub-slot 0..3
    float acc[4] = {0.f, 0.f, 0.f, 0.f};
    for (int base = s0; base < s1; base += 64) {
      int cnt = min(64, s1 - base);
      bool valid = lane < cnt;
      int s = col[valid ? (base + lane) : (s1 - 1)];
      float wv = valid ? wbuf[(unsigned)base + lane] : 0.f;
      float d = wv;
      #pragma unroll
      for (int off = 1; off < 64; off <<= 1) d += __shfl_xor(d, off);
      den += d;
      wlds[lane] = wv;
      slds[lane] = s;
      asm volatile("s_waitcnt lgkmcnt(0)" ::: "memory");
      __builtin_amdgcn_sched_barrier(0);
      #pragma unroll 2
      for (int j = 0; j < cnt; j += 4) {
        int e = j + g;                    // e<=63; entries >=cnt have weight 0
        float wj = wlds[e];
        int sj = slds[e];
        unsigned off = (unsigned)sj * 64 + cb;
        uint2 raw = *(const uint2*)(h + off);
        fma_mix_lo(acc[0], raw.x, wj);
        fma_mix_hi(acc[1], raw.x, wj);
        fma_mix_lo(acc[2], raw.y, wj);
        fma_mix_hi(acc[3], raw.y, wj);
      }
    }
    #pragma unroll
    for (int v = 0; v < 4; v++) {
      acc[v] += __shfl_xor(acc[v], 16);
      acc[v] += __shfl_xor(acc[v], 32);
    }
    if (g == 0) {
      float inv = 1.f / (den + 1e-16f);
      float o[4];
      #pragma unroll
      for (int v = 0; v < 4; v++) {
        float t = acc[v] * inv + bias[cb + v];
        if (ELU) t = t > 0.f ? t : expm1f(t);
        o[v] = t;
      }
      *(float4*)&xout[(size_t)row * 64 + cb] = make_float4(o[0], o[1], o[2], o[3]);
    }
  }
}

// ------------------------- CSR construction --------------------------------
__global__ void k_init(int* deg, float* pool, unsigned short* A2, int N, int B,
                       int Mpad) {
  int i = blockIdx.x * 256 + threadIdx.x;
  if (i < N) deg[i] = 1;                  // self loop
  if (i < B * 64) pool[i] = 0.f;
  int padn = (Mpad - N) * 256;            // zero stride-256 pad rows of A2
  if (i < padn) A2[(size_t)N * 256 + i] = 0;
}

__global__ void k_deg(const int* __restrict__ ei, int* deg, int E) {
  int e = blockIdx.x * 256 + threadIdx.x;
  if (e < E) atomicAdd(&deg[ei[E + e]], 1);
}

__global__ __launch_bounds__(256) void k_scan1(const int* __restrict__ deg,
                                               int* csum, int N, int chunk) {
  int bid = blockIdx.x, t = threadIdx.x;
  int lo = bid * chunk, hi = min(lo + chunk, N);
  int s = 0;
  for (int i = lo + t; i < hi; i += 256) s += deg[i];
  #pragma unroll
  for (int off = 32; off; off >>= 1) s += __shfl_xor(s, off);
  __shared__ int sh[4];
  if ((t & 63) == 0) sh[t >> 6] = s;
  __syncthreads();
  if (t == 0) csum[bid] = sh[0] + sh[1] + sh[2] + sh[3];
}

// scan2 + per-graph counts (batch sorted -> binary search), one block
__global__ __launch_bounds__(256) void k_scan2(const int* __restrict__ csum,
    int* coff, const int* __restrict__ bat, int* cnt, int N, int B) {
  __shared__ int s[256];
  int t = threadIdx.x;
  int v0 = csum[t];
  s[t] = v0;
  for (int off = 1; off < 256; off <<= 1) {
    __syncthreads();
    int v = (t >= off) ? s[t - off] : 0;
    __syncthreads();
    s[t] += v;
  }
  __syncthreads();
  coff[t] = s[t] - v0;
  if (t < B) {
    int lo0 = 0, hi0 = N;
    while (lo0 < hi0) { int mid = (lo0 + hi0) >> 1; if (bat[mid] < t) lo0 = mid + 1; else hi0 = mid; }
    int lo1 = lo0, hi1 = N;
    while (lo1 < hi1) { int mid = (lo1 + hi1) >> 1; if (bat[mid] < t + 1) lo1 = mid + 1; else hi1 = mid; }
    cnt[t] = lo1 - lo0;
  }
}

__global__ __launch_bounds__(256) void k_scan3(const int* __restrict__ deg,
    const int* __restrict__ coff, int* rowptr, int* cursor, int N, int chunk) {
  __shared__ int s[256];
  int bid = blockIdx.x, t = threadIdx.x;
  int i = bid * chunk + t;
  int v = (t < chunk && i < N) ? deg[i] : 0;
  s[t] = v;
  for (int off = 1; off < 256; off <<= 1) {
    __syncthreads();
    int x = (t >= off) ? s[t - off] : 0;
    __syncthreads();
    s[t] += x;
  }
  __syncthreads();
  int excl = s[t] - v + coff[bid];
  if (t < chunk && i < N) {
    rowptr[i] = excl;
    cursor[i] = excl;
    if (i == N - 1) rowptr[N] = excl + v;
  }
}

__global__ void k_scatter(const int* __restrict__ ei, int* cursor, int* col,
                          int* rid, int E, int N) {
  int idx = blockIdx.x * 256 + threadIdx.x;
  if (idx >= E + N) return;
  int s, d;
  if (idx < E) { s = ei[idx]; d = ei[E + idx]; }
  else         { s = d = idx - E; }
  int pos = atomicAdd(&cursor[d], 1);
  col[pos] = s;
  rid[pos] = d;
}

// ------------------------------ pooling ------------------------------------
// 256-thread block = 4 waves, each wave handles 16 consecutive nodes.
__global__ __launch_bounds__(256) void k_pool(const float* __restrict__ xg,
    const int* __restrict__ bat, float* pool, int N) {
  int lane = threadIdx.x & 63, w = threadIdx.x >> 6;
  int base = (blockIdx.x * 4 + w) * 16;
  if (base >= N) return;
  int end = min(base + 16, N);
  float local = 0.f;
  int curb = bat[base];
  for (int n = base; n < end; n++) {
    int b = bat[n];
    if (b != curb) {
      atomicAdd(&pool[curb * 64 + lane], local);
      local = 0.f; curb = b;
    }
    local += xg[(size_t)n * 64 + lane];
  }
  atomicAdd(&pool[curb * 64 + lane], local);
}

__global__ void k_final(const float* __restrict__ pool, const int* __restrict__ cnt,
    const float* __restrict__ Wl, const float* __restrict__ bl,
    float* __restrict__ out, int B) {
  int lane = threadIdx.x;                 // 64 threads
  int c = (lane < B) ? cnt[lane] : 0;
  #pragma unroll
  for (int off = 32; off; off >>= 1) c = max(c, __shfl_xor(c, off));
  float invm = 1.f / (float)c;
  float wl = Wl[lane];
  for (int b = 0; b < B; b++) {
    float ps = pool[b * 64 + lane] * wl;
    #pragma unroll
    for (int off = 32; off; off >>= 1) ps += __shfl_xor(ps, off);
    if (lane == 0) out[b] = ps * invm + bl[0];
  }
}

// ---------------------------------------------------------------------------
extern "C" void kernel_launch(void* const* d_in, const int* in_sizes, int n_in,
                              void* d_out, int out_size, void* d_ws, size_t ws_size,
                              hipStream_t stream)
{
  (void)n_in; (void)ws_size;
  const float* x   = (const float*)d_in[0];
  const int*   ei  = (const int*)d_in[1];
  const int*   bat = (const int*)d_in[2];
  const float* W1  = (const float*)d_in[3];
  const float* as1 = (const float*)d_in[4];
  const float* ad1 = (const float*)d_in[5];
  const float* b1  = (const float*)d_in[6];
  const float* W2  = (const float*)d_in[7];
  const float* as2 = (const float*)d_in[8];
  const float* ad2 = (const float*)d_in[9];
  const float* b2  = (const float*)d_in[10];
  const float* W3  = (const float*)d_in[11];
  const float* as3 = (const float*)d_in[12];
  const float* ad3 = (const float*)d_in[13];
  const float* b3  = (const float*)d_in[14];
  const float* W4  = (const float*)d_in[15];
  const float* as4 = (const float*)d_in[16];
  const float* ad4 = (const float*)d_in[17];
  const float* b4  = (const float*)d_in[18];
  const float* Wl  = (const float*)d_in[19];
  const float* bl  = (const float*)d_in[20];
  float* out = (float*)d_out;

  const int N = in_sizes[0] / 128;
  const int E = in_sizes[1] / 2;
  const int B = out_size;
  const int Mpad = ((N + 127) / 128) * 128;
  const int EN = E + N;

  char* p = (char*)d_ws;
  auto alloc = [&](size_t bytes) -> void* {
    void* r = (void*)p;
    p += ((bytes + 255) & ~(size_t)255);
    return r;
  };
  unsigned short* A2 = (unsigned short*)alloc((size_t)Mpad * 256 * 2);
  unsigned short* hbuf = (unsigned short*)alloc((size_t)N * 256 * 2);
  unsigned short* w2t1 = (unsigned short*)alloc((size_t)256 * 128 * 2);
  unsigned short* w2t2 = (unsigned short*)alloc((size_t)256 * 256 * 2);
  unsigned short* w2t3 = (unsigned short*)alloc((size_t)256 * 256 * 2);
  unsigned short* w2t4 = (unsigned short*)alloc((size_t)128 * 256 * 2);
  float* aAll  = (float*)alloc((size_t)N * 22 * 4);
  float* aSb   = aAll;
  float* aDb   = aAll + (size_t)N * 11;
  float* wbuf  = (float*)alloc((size_t)EN * 8 * 4);
  int*   deg   = (int*)alloc((size_t)N * 4);
  int*   rowptr= (int*)alloc((size_t)(N + 1) * 4);
  int*   cursor= (int*)alloc((size_t)N * 4);
  int*   col   = (int*)alloc((size_t)EN * 4);
  int*   rid   = (int*)alloc((size_t)EN * 4);
  int*   csum  = (int*)alloc(256 * 4);
  int*   coff  = (int*)alloc(256 * 4);
  float* pool  = (float*)alloc((size_t)B * 64 * 4);
  int*   cnt   = (int*)alloc((size_t)B * 4);
  float* xpool = (float*)A2;              // layer-4 output reuses A2 (fp32 [N,64])

  const int chunk = (N + 255) / 256;
  dim3 T(256);
  dim3 T64(64);

  // ---- CSR build + init ----
  k_init<<<dim3((N + 255) / 256), T, 0, stream>>>(deg, pool, A2, N, B, Mpad);
  k_deg<<<dim3((E + 255) / 256), T, 0, stream>>>(ei, deg, E);
  k_scan1<<<dim3(256), T, 0, stream>>>(deg, csum, N, chunk);
  k_scan2<<<dim3(1), T, 0, stream>>>(csum, coff, bat, cnt, N, B);
  k_scan3<<<dim3(256), T, 0, stream>>>(deg, coff, rowptr, cursor, N, chunk);
  k_scatter<<<dim3((EN + 255) / 256), T, 0, stream>>>(ei, cursor, col, rid, E, N);
  hipMemsetAsync(aAll, 0, (size_t)N * 22 * 4, stream);

  // ---- weight + input packing (one kernel) ----
  k_pack_all<<<dim3((196608 + Mpad * 32 + 255) / 256), T, 0, stream>>>(
      W1, W2, W3, W4, w2t1, w2t2, w2t3, w2t4, x, A2, N, Mpad);

  dim3 nrow(N);
  dim3 g2(Mpad / 64, 2), g1(Mpad / 64, 1);
  dim3 gw8((EN * 8 + 255) / 256), gw1((EN + 255) / 256);

  // per-layer alpha buffers inside the arena
  float* aS1 = aSb;                 float* aD1 = aDb;                 // N*8
  float* aS2 = aSb + (size_t)N * 8; float* aD2 = aDb + (size_t)N * 8; // N
  float* aS3 = aSb + (size_t)N * 9; float* aD3 = aDb + (size_t)N * 9; // N
  float* aS4 = aSb + (size_t)N * 10;float* aD4 = aDb + (size_t)N * 10;// N

  // ---- layer 1: [N,128]@[128,256], H=8, ELU ----
  k_gemm_mfma<8><<<g2, T, 0, stream>>>(A2, w2t1, hbuf, as1, ad1, aS1, aD1, N, 128, 256);
  k_wcomp<8><<<gw8, T, 0, stream>>>(aS1, aD1, col, rid, wbuf, EN * 8);
  k_aggregate<8, 256, 1, 1><<<nrow, T64, 0, stream>>>(hbuf, wbuf, rowptr, col, b1,
                                                      nullptr, A2, N);
  // ---- layer 2 ----
  k_gemm_mfma<1><<<g2, T, 0, stream>>>(A2, w2t2, hbuf, as2, ad2, aS2, aD2, N, 256, 256);
  k_wcomp<1><<<gw1, T, 0, stream>>>(aS2, aD2, col, rid, wbuf, EN);
  k_aggregate<1, 256, 1, 1><<<nrow, T64, 0, stream>>>(hbuf, wbuf, rowptr, col, b2,
                                                      nullptr, A2, N);
  // ---- layer 3 ----
  k_gemm_mfma<1><<<g2, T, 0, stream>>>(A2, w2t3, hbuf, as3, ad3, aS3, aD3, N, 256, 256);
  k_wcomp<1><<<gw1, T, 0, stream>>>(aS3, aD3, col, rid, wbuf, EN);
  k_aggregate<1, 256, 1, 1><<<nrow, T64, 0, stream>>>(hbuf, wbuf, rowptr, col, b3,
                                                      nullptr, A2, N);
  // ---- layer 4: [N,256]@[256,64], H=1, no ELU ----
  k_gemm_mfma<1><<<g1, T, 0, stream>>>(A2, w2t4, hbuf, as4, ad4, aS4, aD4, N, 256, 64);
  k_wcomp<1><<<gw1, T, 0, stream>>>(aS4, aD4, col, rid, wbuf, EN);
  k_aggregate<1, 64, 0, 0><<<nrow, T64, 0, stream>>>(hbuf, wbuf, rowptr, col, b4,
                                                     xpool, nullptr, N);

  // ---- pooling + final linear ----
  k_pool<<<dim3((N + 63) / 64), T, 0, stream>>>(xpool, bat, pool, N);
  k_final<<<dim3(1), T64, 0, stream>>>(pool, cnt, Wl, bl, out, B);
}

// Round 16
// 373.025 us; speedup vs baseline: 1.2409x; 1.0369x over previous
//
#include <hip/hip_runtime.h>
#include <math.h>

// ---------------------------------------------------------------------------
// GAT 4-layer forward.
// GEMMs: single-term bf16 MFMA -> fp32 acc; 64x128 tile; alpha dots fused in
// epilogue. h stored fp16.
// Aggregation: ONE WAVE PER ROW (64-thr blocks); weight exp FUSED in phase 1
// (aS[s] gathers are L2-resident); gather phase readlane/LDS broadcast with
// v_fma_mix inner + 32-bit offsets. HC=64: 4 edges/iter via LDS tables.
// ---------------------------------------------------------------------------

typedef __attribute__((ext_vector_type(8))) short short8;
typedef __attribute__((ext_vector_type(4))) float f32x4;

__device__ __forceinline__ unsigned short f2bf(float f) {
  unsigned int u = __builtin_bit_cast(unsigned int, f);
  unsigned int r = u + 0x7FFFu + ((u >> 16) & 1u);   // RNE
  return (unsigned short)(r >> 16);
}
__device__ __forceinline__ float bf2f(unsigned short h) {
  unsigned int u = ((unsigned int)h) << 16;
  return __builtin_bit_cast(float, u);
}
__device__ __forceinline__ unsigned short f2h(float f) {
  _Float16 h = (_Float16)f;
  return __builtin_bit_cast(unsigned short, h);
}
__device__ __forceinline__ float h2f(unsigned short u) {
  return (float)__builtin_bit_cast(_Float16, u);
}

// acc += (f16 lo/hi half of packed) * w   -- single VALU op each
__device__ __forceinline__ void fma_mix_lo(float& acc, unsigned int packed, float w) {
  asm("v_fma_mix_f32 %0, %1, %2, %0 op_sel_hi:[1,0,0]"
      : "+v"(acc) : "v"(packed), "v"(w));
}
__device__ __forceinline__ void fma_mix_hi(float& acc, unsigned int packed, float w) {
  asm("v_fma_mix_f32 %0, %1, %2, %0 op_sel:[1,0,0] op_sel_hi:[1,0,0]"
      : "+v"(acc) : "v"(packed), "v"(w));
}

__device__ __forceinline__ void gload16(const unsigned short* g, unsigned short* l) {
  __builtin_amdgcn_global_load_lds(
      (const __attribute__((address_space(1))) void*)g,
      (__attribute__((address_space(3))) void*)l, 16, 0, 0);
}

// ---------------- MFMA GEMM: C[M,Nc] = A[M,K] @ Wt[Ncpad,K]^T --------------
// 64x128 tile, 4 waves (2 row-halves x 2 col-halves), LDS 24 KB.
template<int H>
__global__ __launch_bounds__(256) void k_gemm_mfma(
    const unsigned short* __restrict__ A2, const unsigned short* __restrict__ Wt,
    unsigned short* __restrict__ C, const float* __restrict__ avec_s,
    const float* __restrict__ avec_d, float* __restrict__ outS,
    float* __restrict__ outD, int M, int Kb, int Nc)
{
  __shared__ unsigned short lds[12288];     // 24 KB: As[64][64] | Bs[128][64]
  unsigned short* As = lds;
  unsigned short* Bs = lds + 4096;
  const int tid = threadIdx.x;
  const int w = tid >> 6, l = tid & 63;
  const int row0 = blockIdx.x * 64, col0 = blockIdx.y * 128;
  const int wr = w >> 1, wc = w & 1;
  const int fr = l & 15, kg = l >> 4;
  const int xr = (fr & 7) << 4;                   // read-side XOR (bytes)
  const int sK = Kb;                              // single bf16 panel
  const int csrc = 8 * ((l & 7) ^ ((l >> 3) & 7));    // pre-swizzled src col
  const int lrow = l >> 3;                        // 8 lanes per row

  f32x4 acc[2][4];
  #pragma unroll
  for (int i = 0; i < 2; i++)
    #pragma unroll
    for (int j = 0; j < 4; j++) acc[i][j] = (f32x4){0.f, 0.f, 0.f, 0.f};

  for (int kp = 0; kp < sK; kp += 64) {
    #pragma unroll
    for (int i = 0; i < 2; i++) {               // A: 8 KB
      int q = w * 2 + i;
      gload16(&A2[(size_t)(row0 + q * 8 + lrow) * sK + (kp + csrc)], &As[q * 512]);
    }
    #pragma unroll
    for (int i = 0; i < 4; i++) {               // B: 16 KB
      int q = w * 4 + i;
      gload16(&Wt[(size_t)(col0 + q * 8 + lrow) * sK + (kp + csrc)], &Bs[q * 512]);
    }
    __syncthreads();
    #pragma unroll
    for (int kk = 0; kk < 2; kk++) {
      short8 a[2], b[4];
      #pragma unroll
      for (int mi = 0; mi < 2; mi++) {
        int r = wr * 32 + mi * 16 + fr;
        int off = r * 128 + ((kk * 64 + kg * 16) ^ xr);
        a[mi] = *(const short8*)((const char*)As + off);
      }
      #pragma unroll
      for (int ni = 0; ni < 4; ni++) {
        int c = wc * 64 + ni * 16 + fr;
        int off = c * 128 + ((kk * 64 + kg * 16) ^ xr);
        b[ni] = *(const short8*)((const char*)Bs + off);
      }
      #pragma unroll
      for (int mi = 0; mi < 2; mi++)
        #pragma unroll
        for (int ni = 0; ni < 4; ni++)
          acc[mi][ni] = __builtin_amdgcn_mfma_f32_16x16x32_bf16(
              a[mi], b[ni], acc[mi][ni], 0, 0, 0);
    }
    __syncthreads();
  }

  // ---- epilogue: acc -> swizzled LDS C-tile 64x128 fp16 ----
  #pragma unroll
  for (int mi = 0; mi < 2; mi++)
    #pragma unroll
    for (int ni = 0; ni < 4; ni++)
      #pragma unroll
      for (int rr = 0; rr < 4; rr++) {
        int row = wr * 32 + mi * 16 + kg * 4 + rr;
        int c = wc * 64 + ni * 16 + fr;
        int sc = c ^ (((row >> 1) & 7) << 3);
        lds[row * 128 + sc] = f2h(acc[mi][ni][rr]);
      }
  __syncthreads();

  // ---- coalesced store + fused alpha ----
  constexpr int RW = (H == 8) ? 4 : 16;
  const int Ch = Nc / H;
  const int rbase = tid >> 4;                     // 0..15
  const int cc = tid & 15;
  const int c0 = cc * 8;
  const int gc0 = col0 + c0;
  float as8[8], ad8[8];
  #pragma unroll
  for (int j = 0; j < 8; j++) {
    bool ok = (gc0 + j) < Nc;
    as8[j] = ok ? avec_s[gc0 + j] : 0.f;
    ad8[j] = ok ? avec_d[gc0 + j] : 0.f;
  }
  #pragma unroll
  for (int i = 0; i < 4; i++) {
    int row = rbase + i * 16;
    int gr = row0 + row;
    int scc = c0 ^ (((row >> 1) & 7) << 3);
    short8 cv = *(const short8*)&lds[row * 128 + scc];
    if (gr < M && gc0 < Nc)
      *(short8*)&C[(size_t)gr * Nc + gc0] = cv;
    float ps = 0.f, pd = 0.f;
    #pragma unroll
    for (int j = 0; j < 8; j++) {
      float cf = h2f((unsigned short)cv[j]);
      ps = fmaf(cf, as8[j], ps);
      pd = fmaf(cf, ad8[j], pd);
    }
    #pragma unroll
    for (int off = 1; off < RW; off <<= 1) {
      ps += __shfl_xor(ps, off);
      pd += __shfl_xor(pd, off);
    }
    if ((tid & (RW - 1)) == 0 && gr < M) {
      int head = gc0 / Ch;                        // 0-add on OOB pad cols
      atomicAdd(&outS[gr * H + head], ps);
      atomicAdd(&outD[gr * H + head], pd);
    }
  }
}

// -------- pack all W fp32 -> bf16 [NCPAD,K] + x fp32 -> bf16 [Mpad,128] ----
__device__ __forceinline__ void packW_one(const float* __restrict__ W,
    unsigned short* __restrict__ Wt, int K, int NC, int idx)
{
  int c = idx / K, k = idx % K;
  unsigned short o = 0;
  if (c < NC) o = f2bf(W[(size_t)k * NC + c]);
  Wt[(size_t)c * K + k] = o;
}

__global__ void k_pack_all(const float* __restrict__ W1, const float* __restrict__ W2,
    const float* __restrict__ W3, const float* __restrict__ W4,
    unsigned short* __restrict__ t1, unsigned short* __restrict__ t2,
    unsigned short* __restrict__ t3, unsigned short* __restrict__ t4,
    const float* __restrict__ x, unsigned short* __restrict__ A2,
    int N, int Mpad)
{
  int idx = blockIdx.x * 256 + threadIdx.x;
  if (idx < 32768)            packW_one(W1, t1, 128, 256, idx);
  else if (idx < 98304)       packW_one(W2, t2, 256, 256, idx - 32768);
  else if (idx < 163840)      packW_one(W3, t3, 256, 256, idx - 98304);
  else if (idx < 196608)      packW_one(W4, t4, 256,  64, idx - 163840);
  else {
    int t = idx - 196608;                        // packX: t in [0, Mpad*32)
    int row = t >> 5;
    if (row >= Mpad) return;
    int c = (t & 31) * 4;
    float4 v = make_float4(0.f, 0.f, 0.f, 0.f);
    if (row < N) v = *(const float4*)&x[(size_t)row * 128 + c];
    unsigned short h0 = f2bf(v.x), h1 = f2bf(v.y), h2 = f2bf(v.z), h3 = f2bf(v.w);
    *(uint2*)&A2[(size_t)row * 128 + c] =
        make_uint2((unsigned)h0 | ((unsigned)h1 << 16),
                   (unsigned)h2 | ((unsigned)h3 << 16));
  }
}

// ---- segment softmax + weighted aggregate, ONE WAVE PER ROW ---------------
// Weight exp fused in phase 1 (aS scattered but L2-resident; aD per-row).
// 64-thread blocks: per-row retirement. HC=64: 4 edges/iter via LDS tables.
template<int H, int HC, int ELU, int SPLIT>
__global__ __launch_bounds__(64) void k_aggregate(const unsigned short* __restrict__ h,
    const float* __restrict__ as, const float* __restrict__ ad,
    const int* __restrict__ rowptr, const int* __restrict__ col,
    const float* __restrict__ bias, float* __restrict__ xout,
    unsigned short* __restrict__ a2out, int N)
{
  const int lane = threadIdx.x;
  const int row = blockIdx.x;
  if (row >= N) return;
  int s0 = rowptr[row], s1 = rowptr[row + 1];
  float den = 0.f;

  if constexpr (HC == 256) {
    constexpr int C = HC / H;
    constexpr int CH = (H == 8) ? 8 : 64;
    __shared__ float wlds[(H == 8) ? 64 : 1];
    const int cb = lane * 4;
    const int hdg = cb / C;
    float adv = (H == 8) ? ad[row * 8 + (lane & 7)] : ad[row];
    float acc[4] = {0.f, 0.f, 0.f, 0.f};
    for (int base = s0; base < s1; base += CH) {
      int cnt = min(CH, s1 - base);
      int eo = (H == 8) ? (lane >> 3) : lane;
      bool valid = eo < cnt;
      int s = col[valid ? (base + eo) : (s1 - 1)];
      float lg = ((H == 8) ? as[s * 8 + (lane & 7)] : as[s]) + adv;
      lg = fmaxf(lg, 0.2f * lg);          // leaky_relu
      float wv = valid ? __expf(lg) : 0.f;
      float d = wv;
      if constexpr (H == 8) {
        d += __shfl_xor(d, 8); d += __shfl_xor(d, 16); d += __shfl_xor(d, 32);
        wlds[lane] = wv;                  // [eo*8+hd]
      } else {
        #pragma unroll
        for (int off = 1; off < 64; off <<= 1) d += __shfl_xor(d, off);
      }
      den += d;                           // H==8: lane holds den[lane&7]
      if (H == 8) {
        asm volatile("s_waitcnt lgkmcnt(0)" ::: "memory");  // wave-local order
      }
      #pragma unroll 4
      for (int j = 0; j < cnt; j++) {
        int sj = __builtin_amdgcn_readlane(s, (H == 8) ? (j * 8) : j);
        float wj;
        if constexpr (H == 8) {
          wj = wlds[j * 8 + hdg];
        } else {
          wj = __builtin_bit_cast(float,
                __builtin_amdgcn_readlane(__builtin_bit_cast(int, wv), j));
        }
        unsigned off = (unsigned)sj * HC + cb;
        uint2 raw = *(const uint2*)(h + off);
        fma_mix_lo(acc[0], raw.x, wj);
        fma_mix_hi(acc[1], raw.x, wj);
        fma_mix_lo(acc[2], raw.y, wj);
        fma_mix_hi(acc[3], raw.y, wj);
      }
    }
    if (H == 8) den = __shfl(den, hdg);
    float inv = 1.f / (den + 1e-16f);
    float o[4];
    #pragma unroll
    for (int v = 0; v < 4; v++) {
      float t = acc[v] * inv + bias[cb + v];
      if (ELU) t = t > 0.f ? t : expm1f(t);
      o[v] = t;
    }
    if constexpr (SPLIT) {
      unsigned short hi[4];
      #pragma unroll
      for (int v = 0; v < 4; v++) hi[v] = f2bf(o[v]);
      *(uint2*)&a2out[(size_t)row * HC + cb] =
          make_uint2((unsigned)hi[0] | ((unsigned)hi[1] << 16),
                     (unsigned)hi[2] | ((unsigned)hi[3] << 16));
    } else {
      *(float4*)&xout[(size_t)row * HC + cb] = make_float4(o[0], o[1], o[2], o[3]);
    }
  } else {
    // ---- HC == 64, H == 1: 4 edges/iteration, 16 lanes per edge ----
    __shared__ float wlds[64];
    __shared__ int   slds[64];
    const int cb = (lane & 15) * 4;       // 4 fp16 channels (8 B)
    const int g = lane >> 4;              // edge sub-slot 0..3
    float adv = ad[row];
    float acc[4] = {0.f, 0.f, 0.f, 0.f};
    for (int base = s0; base < s1; base += 64) {
      int cnt = min(64, s1 - base);
      bool valid = lane < cnt;
      int s = col[valid ? (base + lane) : (s1 - 1)];
      float lg = as[s] + adv;
      lg = fmaxf(lg, 0.2f * lg);
      float wv = valid ? __expf(lg) : 0.f;
      float d = wv;
      #pragma unroll
      for (int off = 1; off < 64; off <<= 1) d += __shfl_xor(d, off);
      den += d;
      wlds[lane] = wv;
      slds[lane] = s;
      asm volatile("s_waitcnt lgkmcnt(0)" ::: "memory");
      __builtin_amdgcn_sched_barrier(0);
      #pragma unroll 2
      for (int j = 0; j < cnt; j += 4) {
        int e = j + g;                    // e<=63; entries >=cnt have weight 0
        float wj = wlds[e];
        int sj = slds[e];
        unsigned off = (unsigned)sj * 64 + cb;
        uint2 raw = *(const uint2*)(h + off);
        fma_mix_lo(acc[0], raw.x, wj);
        fma_mix_hi(acc[1], raw.x, wj);
        fma_mix_lo(acc[2], raw.y, wj);
        fma_mix_hi(acc[3], raw.y, wj);
      }
    }
    #pragma unroll
    for (int v = 0; v < 4; v++) {
      acc[v] += __shfl_xor(acc[v], 16);
      acc[v] += __shfl_xor(acc[v], 32);
    }
    if (g == 0) {
      float inv = 1.f / (den + 1e-16f);
      float o[4];
      #pragma unroll
      for (int v = 0; v < 4; v++) {
        float t = acc[v] * inv + bias[cb + v];
        if (ELU) t = t > 0.f ? t : expm1f(t);
        o[v] = t;
      }
      *(float4*)&xout[(size_t)row * 64 + cb] = make_float4(o[0], o[1], o[2], o[3]);
    }
  }
}

// ------------------------- CSR construction --------------------------------
__global__ void k_init(int* deg, float* pool, unsigned short* A2, int N, int B,
                       int Mpad) {
  int i = blockIdx.x * 256 + threadIdx.x;
  if (i < N) deg[i] = 1;                  // self loop
  if (i < B * 64) pool[i] = 0.f;
  int padn = (Mpad - N) * 256;            // zero stride-256 pad rows of A2
  if (i < padn) A2[(size_t)N * 256 + i] = 0;
}

__global__ void k_deg(const int* __restrict__ ei, int* deg, int E) {
  int e = blockIdx.x * 256 + threadIdx.x;
  if (e < E) atomicAdd(&deg[ei[E + e]], 1);
}

__global__ __launch_bounds__(256) void k_scan1(const int* __restrict__ deg,
                                               int* csum, int N, int chunk) {
  int bid = blockIdx.x, t = threadIdx.x;
  int lo = bid * chunk, hi = min(lo + chunk, N);
  int s = 0;
  for (int i = lo + t; i < hi; i += 256) s += deg[i];
  #pragma unroll
  for (int off = 32; off; off >>= 1) s += __shfl_xor(s, off);
  __shared__ int sh[4];
  if ((t & 63) == 0) sh[t >> 6] = s;
  __syncthreads();
  if (t == 0) csum[bid] = sh[0] + sh[1] + sh[2] + sh[3];
}

// scan2 + per-graph counts (batch sorted -> binary search), one block
__global__ __launch_bounds__(256) void k_scan2(const int* __restrict__ csum,
    int* coff, const int* __restrict__ bat, int* cnt, int N, int B) {
  __shared__ int s[256];
  int t = threadIdx.x;
  int v0 = csum[t];
  s[t] = v0;
  for (int off = 1; off < 256; off <<= 1) {
    __syncthreads();
    int v = (t >= off) ? s[t - off] : 0;
    __syncthreads();
    s[t] += v;
  }
  __syncthreads();
  coff[t] = s[t] - v0;
  if (t < B) {
    int lo0 = 0, hi0 = N;
    while (lo0 < hi0) { int mid = (lo0 + hi0) >> 1; if (bat[mid] < t) lo0 = mid + 1; else hi0 = mid; }
    int lo1 = lo0, hi1 = N;
    while (lo1 < hi1) { int mid = (lo1 + hi1) >> 1; if (bat[mid] < t + 1) lo1 = mid + 1; else hi1 = mid; }
    cnt[t] = lo1 - lo0;
  }
}

__global__ __launch_bounds__(256) void k_scan3(const int* __restrict__ deg,
    const int* __restrict__ coff, int* rowptr, int* cursor, int N, int chunk) {
  __shared__ int s[256];
  int bid = blockIdx.x, t = threadIdx.x;
  int i = bid * chunk + t;
  int v = (t < chunk && i < N) ? deg[i] : 0;
  s[t] = v;
  for (int off = 1; off < 256; off <<= 1) {
    __syncthreads();
    int x = (t >= off) ? s[t - off] : 0;
    __syncthreads();
    s[t] += x;
  }
  __syncthreads();
  int excl = s[t] - v + coff[bid];
  if (t < chunk && i < N) {
    rowptr[i] = excl;
    cursor[i] = excl;
    if (i == N - 1) rowptr[N] = excl + v;
  }
}

__global__ void k_scatter(const int* __restrict__ ei, int* cursor, int* col,
                          int E, int N) {
  int idx = blockIdx.x * 256 + threadIdx.x;
  if (idx >= E + N) return;
  int s, d;
  if (idx < E) { s = ei[idx]; d = ei[E + idx]; }
  else         { s = d = idx - E; }
  int pos = atomicAdd(&cursor[d], 1);
  col[pos] = s;
}

// ------------------------------ pooling ------------------------------------
// 256-thread block = 4 waves, each wave handles 16 consecutive nodes.
__global__ __launch_bounds__(256) void k_pool(const float* __restrict__ xg,
    const int* __restrict__ bat, float* pool, int N) {
  int lane = threadIdx.x & 63, w = threadIdx.x >> 6;
  int base = (blockIdx.x * 4 + w) * 16;
  if (base >= N) return;
  int end = min(base + 16, N);
  float local = 0.f;
  int curb = bat[base];
  for (int n = base; n < end; n++) {
    int b = bat[n];
    if (b != curb) {
      atomicAdd(&pool[curb * 64 + lane], local);
      local = 0.f; curb = b;
    }
    local += xg[(size_t)n * 64 + lane];
  }
  atomicAdd(&pool[curb * 64 + lane], local);
}

__global__ void k_final(const float* __restrict__ pool, const int* __restrict__ cnt,
    const float* __restrict__ Wl, const float* __restrict__ bl,
    float* __restrict__ out, int B) {
  int lane = threadIdx.x;                 // 64 threads
  int c = (lane < B) ? cnt[lane] : 0;
  #pragma unroll
  for (int off = 32; off; off >>= 1) c = max(c, __shfl_xor(c, off));
  float invm = 1.f / (float)c;
  float wl = Wl[lane];
  for (int b = 0; b < B; b++) {
    float ps = pool[b * 64 + lane] * wl;
    #pragma unroll
    for (int off = 32; off; off >>= 1) ps += __shfl_xor(ps, off);
    if (lane == 0) out[b] = ps * invm + bl[0];
  }
}

// ---------------------------------------------------------------------------
extern "C" void kernel_launch(void* const* d_in, const int* in_sizes, int n_in,
                              void* d_out, int out_size, void* d_ws, size_t ws_size,
                              hipStream_t stream)
{
  (void)n_in; (void)ws_size;
  const float* x   = (const float*)d_in[0];
  const int*   ei  = (const int*)d_in[1];
  const int*   bat = (const int*)d_in[2];
  const float* W1  = (const float*)d_in[3];
  const float* as1 = (const float*)d_in[4];
  const float* ad1 = (const float*)d_in[5];
  const float* b1  = (const float*)d_in[6];
  const float* W2  = (const float*)d_in[7];
  const float* as2 = (const float*)d_in[8];
  const float* ad2 = (const float*)d_in[9];
  const float* b2  = (const float*)d_in[10];
  const float* W3  = (const float*)d_in[11];
  const float* as3 = (const float*)d_in[12];
  const float* ad3 = (const float*)d_in[13];
  const float* b3  = (const float*)d_in[14];
  const float* W4  = (const float*)d_in[15];
  const float* as4 = (const float*)d_in[16];
  const float* ad4 = (const float*)d_in[17];
  const float* b4  = (const float*)d_in[18];
  const float* Wl  = (const float*)d_in[19];
  const float* bl  = (const float*)d_in[20];
  float* out = (float*)d_out;

  const int N = in_sizes[0] / 128;
  const int E = in_sizes[1] / 2;
  const int B = out_size;
  const int Mpad = ((N + 127) / 128) * 128;
  const int EN = E + N;

  char* p = (char*)d_ws;
  auto alloc = [&](size_t bytes) -> void* {
    void* r = (void*)p;
    p += ((bytes + 255) & ~(size_t)255);
    return r;
  };
  unsigned short* A2 = (unsigned short*)alloc((size_t)Mpad * 256 * 2);
  unsigned short* hbuf = (unsigned short*)alloc((size_t)N * 256 * 2);
  unsigned short* w2t1 = (unsigned short*)alloc((size_t)256 * 128 * 2);
  unsigned short* w2t2 = (unsigned short*)alloc((size_t)256 * 256 * 2);
  unsigned short* w2t3 = (unsigned short*)alloc((size_t)256 * 256 * 2);
  unsigned short* w2t4 = (unsigned short*)alloc((size_t)128 * 256 * 2);
  float* aAll  = (float*)alloc((size_t)N * 22 * 4);
  float* aSb   = aAll;
  float* aDb   = aAll + (size_t)N * 11;
  int*   deg   = (int*)alloc((size_t)N * 4);
  int*   rowptr= (int*)alloc((size_t)(N + 1) * 4);
  int*   cursor= (int*)alloc((size_t)N * 4);
  int*   col   = (int*)alloc((size_t)EN * 4);
  int*   csum  = (int*)alloc(256 * 4);
  int*   coff  = (int*)alloc(256 * 4);
  float* pool  = (float*)alloc((size_t)B * 64 * 4);
  int*   cnt   = (int*)alloc((size_t)B * 4);
  float* xpool = (float*)A2;              // layer-4 output reuses A2 (fp32 [N,64])

  const int chunk = (N + 255) / 256;
  dim3 T(256);
  dim3 T64(64);

  // ---- CSR build + init ----
  k_init<<<dim3((N + 255) / 256), T, 0, stream>>>(deg, pool, A2, N, B, Mpad);
  k_deg<<<dim3((E + 255) / 256), T, 0, stream>>>(ei, deg, E);
  k_scan1<<<dim3(256), T, 0, stream>>>(deg, csum, N, chunk);
  k_scan2<<<dim3(1), T, 0, stream>>>(csum, coff, bat, cnt, N, B);
  k_scan3<<<dim3(256), T, 0, stream>>>(deg, coff, rowptr, cursor, N, chunk);
  k_scatter<<<dim3((EN + 255) / 256), T, 0, stream>>>(ei, cursor, col, E, N);
  hipMemsetAsync(aAll, 0, (size_t)N * 22 * 4, stream);

  // ---- weight + input packing (one kernel) ----
  k_pack_all<<<dim3((196608 + Mpad * 32 + 255) / 256), T, 0, stream>>>(
      W1, W2, W3, W4, w2t1, w2t2, w2t3, w2t4, x, A2, N, Mpad);

  dim3 nrow(N);
  dim3 g2(Mpad / 64, 2), g1(Mpad / 64, 1);

  // per-layer alpha buffers inside the arena
  float* aS1 = aSb;                 float* aD1 = aDb;                 // N*8
  float* aS2 = aSb + (size_t)N * 8; float* aD2 = aDb + (size_t)N * 8; // N
  float* aS3 = aSb + (size_t)N * 9; float* aD3 = aDb + (size_t)N * 9; // N
  float* aS4 = aSb + (size_t)N * 10;float* aD4 = aDb + (size_t)N * 10;// N

  // ---- layer 1: [N,128]@[128,256], H=8, ELU ----
  k_gemm_mfma<8><<<g2, T, 0, stream>>>(A2, w2t1, hbuf, as1, ad1, aS1, aD1, N, 128, 256);
  k_aggregate<8, 256, 1, 1><<<nrow, T64, 0, stream>>>(hbuf, aS1, aD1, rowptr, col, b1,
                                                      nullptr, A2, N);
  // ---- layer 2 ----
  k_gemm_mfma<1><<<g2, T, 0, stream>>>(A2, w2t2, hbuf, as2, ad2, aS2, aD2, N, 256, 256);
  k_aggregate<1, 256, 1, 1><<<nrow, T64, 0, stream>>>(hbuf, aS2, aD2, rowptr, col, b2,
                                                      nullptr, A2, N);
  // ---- layer 3 ----
  k_gemm_mfma<1><<<g2, T, 0, stream>>>(A2, w2t3, hbuf, as3, ad3, aS3, aD3, N, 256, 256);
  k_aggregate<1, 256, 1, 1><<<nrow, T64, 0, stream>>>(hbuf, aS3, aD3, rowptr, col, b3,
                                                      nullptr, A2, N);
  // ---- layer 4: [N,256]@[256,64], H=1, no ELU ----
  k_gemm_mfma<1><<<g1, T, 0, stream>>>(A2, w2t4, hbuf, as4, ad4, aS4, aD4, N, 256, 64);
  k_aggregate<1, 64, 0, 0><<<nrow, T64, 0, stream>>>(hbuf, aS4, aD4, rowptr, col, b4,
                                                     xpool, nullptr, N);

  // ---- pooling + final linear ----
  k_pool<<<dim3((N + 63) / 64), T, 0, stream>>>(xpool, bat, pool, N);
  k_final<<<dim3(1), T64, 0, stream>>>(pool, cnt, Wl, bl, out, B);
}